// Round 11
// baseline (175.798 us; speedup 1.0000x reference)
//
#include <hip/hip_runtime.h>
#include <hip/hip_bf16.h>
#include <cstdint>

#define DIMC 1024
#define HEADS 16
#define DHH 64
#define SEQ 4096
#define LATENT 1024
#define HISTC 3072
#define BATCH 2

typedef __attribute__((ext_vector_type(8))) __bf16 bf16x8;
typedef __attribute__((ext_vector_type(4))) float f32x4;
typedef __attribute__((ext_vector_type(16))) float f32x16;

// ---------------- fused prep: x->bf16, 3 weights->bf16, RoPE cos/sin table ----
__global__ void k_prep(const float* __restrict__ x, const float* __restrict__ Wq,
                       const float* __restrict__ Wkv, const float* __restrict__ Wo,
                       __bf16* __restrict__ x16, __bf16* __restrict__ wq16,
                       __bf16* __restrict__ wkv16, __bf16* __restrict__ wo16,
                       float2* __restrict__ cs) {
  int bidx = blockIdx.x;
  if (bidx < 2048) {
    int base = bidx * 256 + threadIdx.x;
#pragma unroll
    for (int k = 0; k < 4; ++k) {
      int i = base + k * 524288;
      float4 v = reinterpret_cast<const float4*>(x)[i];
      union { __bf16 h[4]; uint64_t u; } p;
      p.h[0] = (__bf16)v.x; p.h[1] = (__bf16)v.y;
      p.h[2] = (__bf16)v.z; p.h[3] = (__bf16)v.w;
      reinterpret_cast<uint64_t*>(x16)[i] = p.u;
    }
  } else if (bidx < 3584) {
    int id = bidx - 2048;
    const float* src; __bf16* dst;
    if (id < 512) { src = Wq; dst = wq16; }
    else if (id < 1024) { src = Wkv; dst = wkv16; id -= 512; }
    else { src = Wo; dst = wo16; id -= 1024; }
#pragma unroll
    for (int k = 0; k < 2; ++k) {
      int idx = id * 512 + k * 256 + threadIdx.x;
      float4 v = reinterpret_cast<const float4*>(src)[idx];
      union { __bf16 h[4]; uint64_t u; } p;
      p.h[0] = (__bf16)v.x; p.h[1] = (__bf16)v.y;
      p.h[2] = (__bf16)v.z; p.h[3] = (__bf16)v.w;
      reinterpret_cast<uint64_t*>(dst)[idx] = p.u;
    }
  } else {
    int idx = (bidx - 3584) * 256 + threadIdx.x;   // 4096*32 entries
    int pos = idx >> 5, f = idx & 31;
    float invf = exp2f(-(float)f * 0.41524101186f);  // log2(10000)/32
    float s, c;
    sincosf((float)pos * invf, &s, &c);
    cs[idx] = make_float2(c, s);
  }
}

// ---------------- async global->LDS 16B ----------------
__device__ __forceinline__ void gload16(void* lds, const void* g) {
  __builtin_amdgcn_global_load_lds(
      (const __attribute__((address_space(1))) unsigned int*)g,
      (__attribute__((address_space(3))) unsigned int*)lds, 16, 0, 0);
}

// ---------------- plain GEMM (o-proj): C = A @ Bw^T + bias ----
template<int BIAS>
__launch_bounds__(256)
__global__ void k_gemm(const __bf16* __restrict__ A, const __bf16* __restrict__ Bw,
                       float* __restrict__ C, const float* __restrict__ bias,
                       int M, int N, int K) {
  __shared__ __align__(16) char lds[16384];
  const int t = threadIdx.x;
  const int l = t & 63, w = t >> 6;
  const int wr = w >> 1, wc = w & 1;
  const int mblocks = M >> 7;
  const int m0 = (blockIdx.x % mblocks) * 128, n0 = (blockIdx.x / mblocks) * 128;
  const int lrow = l & 15, lk = l >> 4;
  f32x4 acc[4][4] = {};

  for (int k0 = 0; k0 < K; k0 += 32) {
    if (k0) __syncthreads();
#pragma unroll
    for (int i = 0; i < 2; ++i) {
      int c = i * 256 + t;
      int row = c >> 2, kc = c & 3;
      gload16(lds + c * 16, A + (size_t)(m0 + row) * K + k0 + kc * 8);
      gload16(lds + 8192 + c * 16, Bw + (size_t)(n0 + row) * K + k0 + kc * 8);
    }
    __syncthreads();
    bf16x8 af[4], bfr[4];
#pragma unroll
    for (int m = 0; m < 4; ++m)
      af[m] = *reinterpret_cast<const bf16x8*>(lds + (wr * 64 + m * 16 + lrow) * 64 + lk * 16);
#pragma unroll
    for (int n = 0; n < 4; ++n)
      bfr[n] = *reinterpret_cast<const bf16x8*>(lds + 8192 + (wc * 64 + n * 16 + lrow) * 64 + lk * 16);
#pragma unroll
    for (int m = 0; m < 4; ++m)
#pragma unroll
      for (int n = 0; n < 4; ++n)
        acc[m][n] = __builtin_amdgcn_mfma_f32_16x16x32_bf16(af[m], bfr[n], acc[m][n], 0, 0, 0);
  }

#pragma unroll
  for (int m = 0; m < 4; ++m)
#pragma unroll
    for (int n = 0; n < 4; ++n)
#pragma unroll
      for (int r = 0; r < 4; ++r) {
        int row = m0 + wr * 64 + m * 16 + (l >> 4) * 4 + r;
        int col = n0 + wc * 64 + n * 16 + (l & 15);
        float v = acc[m][n][r];
        if (BIAS) v += bias[col];
        C[(size_t)row * N + col] = v;
      }
}

// ---------------- fused QKV GEMM: kv-proj(+RoPE+LN) and q-proj(+RoPE+scale) ----
__launch_bounds__(256)
__global__ void k_gemmqkv(const __bf16* __restrict__ x16,
                          const __bf16* __restrict__ wkv16,
                          const __bf16* __restrict__ wq16,
                          __bf16* __restrict__ kvn, __bf16* __restrict__ kvnT,
                          __bf16* __restrict__ qb,
                          const float* __restrict__ gamma,
                          const float* __restrict__ beta,
                          const float2* __restrict__ cstab) {
  __shared__ __align__(16) char lds[16384];
  const int t = threadIdx.x, l = t & 63, w = t >> 6;
  const int wr = w >> 1, wc = w & 1;
  const int by = blockIdx.x % 80;
  const bool isq = by >= 64;
  const int m0 = (isq ? (by - 64) : by) * 128;
  const int n0 = (blockIdx.x / 80) * 128;
  const __bf16* Bw = isq ? wq16 : wkv16;
  const int lrow = l & 15, lk = l >> 4;
  f32x4 acc[4][4] = {};

  for (int k0 = 0; k0 < 1024; k0 += 32) {
    if (k0) __syncthreads();
#pragma unroll
    for (int i = 0; i < 2; ++i) {
      int c = i * 256 + t;
      int row = c >> 2, kc = c & 3;
      int mi = m0 + row;
      if (isq) mi += HISTC + (mi >> 10) * HISTC;
      gload16(lds + c * 16, x16 + (size_t)mi * 1024 + k0 + kc * 8);
      gload16(lds + 8192 + c * 16, Bw + (size_t)(n0 + row) * 1024 + k0 + kc * 8);
    }
    __syncthreads();
    bf16x8 af[4], bfr[4];
#pragma unroll
    for (int m = 0; m < 4; ++m)
      af[m] = *reinterpret_cast<const bf16x8*>(lds + (wr * 64 + m * 16 + lrow) * 64 + lk * 16);
#pragma unroll
    for (int n = 0; n < 4; ++n)
      bfr[n] = *reinterpret_cast<const bf16x8*>(lds + 8192 + (wc * 64 + n * 16 + lrow) * 64 + lk * 16);
#pragma unroll
    for (int m = 0; m < 4; ++m)
#pragma unroll
      for (int n = 0; n < 4; ++n)
        acc[m][n] = __builtin_amdgcn_mfma_f32_16x16x32_bf16(af[m], bfr[n], acc[m][n], 0, 0, 0);
  }

  // ---- RoPE in place via table ----
#pragma unroll
  for (int m = 0; m < 4; ++m)
#pragma unroll
    for (int r = 0; r < 4; ++r) {
      int rl = wr * 64 + m * 16 + lk * 4 + r;
      int pos = isq ? (HISTC + ((m0 + rl) & 1023)) : ((m0 + rl) & 4095);
      float2 cs0 = cstab[pos * 32 + lrow];
      float2 cs1 = cstab[pos * 32 + 16 + lrow];
      float a0 = acc[m][0][r], a2 = acc[m][2][r];
      acc[m][0][r] = a0 * cs0.x - a2 * cs0.y;
      acc[m][2][r] = a2 * cs0.x + a0 * cs0.y;
      float a1 = acc[m][1][r], a3 = acc[m][3][r];
      acc[m][1][r] = a1 * cs1.x - a3 * cs1.y;
      acc[m][3][r] = a3 * cs1.x + a1 * cs1.y;
    }

  const int h = (n0 + wc * 64) >> 6;
  if (!isq) {
    float g4[4], b4[4];
#pragma unroll
    for (int n = 0; n < 4; ++n) { g4[n] = gamma[n * 16 + lrow]; b4[n] = beta[n * 16 + lrow]; }
#pragma unroll
    for (int m = 0; m < 4; ++m)
#pragma unroll
      for (int r = 0; r < 4; ++r) {
        float s1 = acc[m][0][r] + acc[m][1][r] + acc[m][2][r] + acc[m][3][r];
        float s2 = acc[m][0][r] * acc[m][0][r] + acc[m][1][r] * acc[m][1][r] +
                   acc[m][2][r] * acc[m][2][r] + acc[m][3][r] * acc[m][3][r];
#pragma unroll
        for (int mk = 1; mk < 16; mk <<= 1) {
          s1 += __shfl_xor(s1, mk);
          s2 += __shfl_xor(s2, mk);
        }
        float mu = s1 * 0.015625f;
        float var = s2 * 0.015625f - mu * mu;
        float inv = rsqrtf(var + 1e-5f);
#pragma unroll
        for (int n = 0; n < 4; ++n)
          acc[m][n][r] = (acc[m][n][r] - mu) * inv * g4[n] + b4[n];
      }
    const size_t hb = (size_t)((m0 >> 12) * HEADS + h);
#pragma unroll
    for (int m = 0; m < 4; ++m)
#pragma unroll
      for (int r = 0; r < 4; ++r) {
        int pos = (m0 + wr * 64 + m * 16 + lk * 4 + r) & 4095;
#pragma unroll
        for (int n = 0; n < 4; ++n)
          kvn[(hb * SEQ + pos) * DHH + n * 16 + lrow] = (__bf16)acc[m][n][r];
      }
#pragma unroll
    for (int m = 0; m < 4; ++m) {
      int pos0 = (m0 + wr * 64 + m * 16 + lk * 4) & 4095;
      int sp = (pos0 & ~12) | ((pos0 & 4) << 1) | ((pos0 & 8) >> 1);
#pragma unroll
      for (int n = 0; n < 4; ++n) {
        union { __bf16 hh[4]; uint64_t u; } pk;
#pragma unroll
        for (int r = 0; r < 4; ++r) pk.hh[r] = (__bf16)acc[m][n][r];
        *reinterpret_cast<uint64_t*>(kvnT + (hb * DHH + n * 16 + lrow) * SEQ + sp) = pk.u;
      }
    }
  } else {
    const size_t hb = (size_t)((m0 >> 10) * HEADS + h);
#pragma unroll
    for (int m = 0; m < 4; ++m)
#pragma unroll
      for (int r = 0; r < 4; ++r) {
        int qi = (m0 + wr * 64 + m * 16 + lk * 4 + r) & 1023;
#pragma unroll
        for (int n = 0; n < 4; ++n)
          qb[(hb * LATENT + qi) * DHH + n * 16 + lrow] =
              (__bf16)(acc[m][n][r] * 0.18033688011112042f);
      }
  }
}

// ---------------- helpers for flash ----------------
__device__ __forceinline__ float fexp2(float x) {
#if __has_builtin(__builtin_amdgcn_exp2f)
  return __builtin_amdgcn_exp2f(x);
#else
  return exp2f(x);
#endif
}

__device__ __forceinline__ unsigned pk2(float a, float b) {
  union { __bf16 h[2]; unsigned u; } x;
  x.h[0] = (__bf16)a; x.h[1] = (__bf16)b;
  return x.u;
}

// ---------------- flash attention v8 ----------------
// flash5 loop (92 VGPR, 18.4KB LDS) + 2-way j-split ACROSS BLOCKS: grid 2048
// -> 5 blocks/CU resident (VGPR-capped 20 waves/CU vs 16). Each block merges
// its 4 waves and writes a partial (O fp32, m, l) to ws; k_fmerge combines the
// 2 partials per (b,h,itile). itile flipped for jh=1 -> per-CU work constant.
__launch_bounds__(256)
__global__ void k_flash8(const __bf16* __restrict__ qb, const __bf16* __restrict__ kvn,
                         const __bf16* __restrict__ kvnT, float* __restrict__ part) {
  const int bid = blockIdx.x;
  const int grp = bid >> 9;                       // [0,4)
  const int jh = (bid >> 8) & 1;
  const int bh = (bid & 7) + 8 * grp;             // [0,32)
  int itile = (bid >> 3) & 31;
  if (jh) itile = 31 - itile;                     // CU work balance
  const int h = bh & 15, b = bh >> 4;
  const int t = threadIdx.x, l = t & 63, w = t >> 6;
  const int q = l & 31, hi = l >> 5;
  const int iw = itile * 32;
  const int i = iw + q;
  const __bf16* qbase = qb + ((size_t)(b * HEADS + h) * LATENT + iw) * DHH;
  const __bf16* kbase = kvn + (size_t)(b * HEADS + h) * SEQ * DHH;
  const __bf16* vbase = kvnT + (size_t)(b * HEADS + h) * DHH * SEQ;

  __shared__ __align__(16) char smem[4][4352];   // per-wave: V [64][32] | merge Ow [32][33]
  __shared__ float Mlds[4][32];
  __shared__ float Llds[4][32];
  __bf16 (*Vw)[32] = reinterpret_cast<__bf16(*)[32]>(smem[w]);

  bf16x8 qf[4];
#pragma unroll
  for (int c = 0; c < 4; ++c)
    qf[c] = *reinterpret_cast<const bf16x8*>(qbase + (size_t)q * DHH + c * 16 + hi * 8);

  const f32x16 Z = {};
  f32x16 O0 = {}, O1 = {};
  float m_run = -INFINITY, lacc = 0.f;

  const int nt = itile + 97;                     // 32-key tiles total
  const int s = jh * 4 + w;                      // 8-way split
  const int t0 = (nt * s) >> 3, t1 = (nt * (s + 1)) >> 3;

  const int srow = l >> 2, scol = l & 3;
  const int wchunk = (scol ^ (srow & 3)) * 8;    // XOR-swizzled 16B chunk slot
  const int sx = q & 3;
  bf16x8 vreg[4], kreg[4];
#pragma unroll
  for (int ii = 0; ii < 4; ++ii)
    vreg[ii] = *reinterpret_cast<const bf16x8*>(
        vbase + (size_t)(ii * 16 + srow) * SEQ + t0 * 32 + scol * 8);
#pragma unroll
  for (int c = 0; c < 4; ++c)
    kreg[c] = *reinterpret_cast<const bf16x8*>(
        kbase + (size_t)(t0 * 32 + q) * DHH + c * 16 + hi * 8);

  for (int tt = t0; tt < t1; ++tt) {
    const int j0 = tt * 32;
    // QK^T first (consumes kreg at issue)
    f32x16 S = __builtin_amdgcn_mfma_f32_32x32x16_bf16(kreg[0], qf[0], Z, 0, 0, 0);
    S = __builtin_amdgcn_mfma_f32_32x32x16_bf16(kreg[1], qf[1], S, 0, 0, 0);
    S = __builtin_amdgcn_mfma_f32_32x32x16_bf16(kreg[2], qf[2], S, 0, 0, 0);
    S = __builtin_amdgcn_mfma_f32_32x32x16_bf16(kreg[3], qf[3], S, 0, 0, 0);
    // commit V(tt) into swizzled LDS (wave-private)
#pragma unroll
    for (int ii = 0; ii < 4; ++ii)
      *reinterpret_cast<bf16x8*>(&Vw[ii * 16 + srow][wchunk]) = vreg[ii];
    // clamped prefetch of tile tt+1
    const int tn = (tt + 1 < t1) ? tt + 1 : tt;
#pragma unroll
    for (int ii = 0; ii < 4; ++ii)
      vreg[ii] = *reinterpret_cast<const bf16x8*>(
          vbase + (size_t)(ii * 16 + srow) * SEQ + tn * 32 + scol * 8);
#pragma unroll
    for (int c = 0; c < 4; ++c)
      kreg[c] = *reinterpret_cast<const bf16x8*>(
          kbase + (size_t)(tn * 32 + q) * DHH + c * 16 + hi * 8);
    // mask: j - HIST > i
    if (j0 + 31 > iw + HISTC) {
#pragma unroll
      for (int r = 0; r < 16; ++r) {
        int j = j0 + (r & 3) + 8 * (r >> 2) + 4 * hi;
        if (j > i + HISTC) S[r] = -1e30f;
      }
    }
    // lane-local max
    float u1 = fmaxf(fmaxf(S[0], S[1]), S[2]);
    float u2 = fmaxf(fmaxf(S[3], S[4]), S[5]);
    float u3 = fmaxf(fmaxf(S[6], S[7]), S[8]);
    float u4 = fmaxf(fmaxf(S[9], S[10]), S[11]);
    float u5 = fmaxf(fmaxf(S[12], S[13]), S[14]);
    float pm = fmaxf(fmaxf(fmaxf(u1, u2), u3), fmaxf(fmaxf(u4, u5), S[15]));
    // defer-max
    if (__any(pm > m_run + 8.0f)) {
      pm = fmaxf(pm, __shfl_xor(pm, 32));
      float mn = fmaxf(m_run, pm);
      float sc = fexp2(m_run - mn);
      m_run = mn;
      lacc *= sc;
#pragma unroll
      for (int r = 0; r < 16; ++r) { O0[r] *= sc; O1[r] *= sc; }
    }
    // P = 2^(S-m); lane-local sum
    float p[16];
#pragma unroll
    for (int r = 0; r < 16; ++r) p[r] = fexp2(S[r] - m_run);
    float s8[8];
#pragma unroll
    for (int r = 0; r < 8; ++r) s8[r] = p[r] + p[r + 8];
    lacc += ((s8[0] + s8[4]) + (s8[1] + s8[5])) + ((s8[2] + s8[6]) + (s8[3] + s8[7]));
    // PV B-frags = own p's (sigma-permuted V)
    union { unsigned u[4]; bf16x8 v; } pf0, pf1;
    pf0.u[0] = pk2(p[0], p[1]);   pf0.u[1] = pk2(p[2], p[3]);
    pf0.u[2] = pk2(p[4], p[5]);   pf0.u[3] = pk2(p[6], p[7]);
    pf1.u[0] = pk2(p[8], p[9]);   pf1.u[1] = pk2(p[10], p[11]);
    pf1.u[2] = pk2(p[12], p[13]); pf1.u[3] = pk2(p[14], p[15]);
    {
      bf16x8 va00 = *reinterpret_cast<const bf16x8*>(&Vw[q][(hi ^ sx) * 8]);
      bf16x8 va01 = *reinterpret_cast<const bf16x8*>(&Vw[q][((2 + hi) ^ sx) * 8]);
      bf16x8 va10 = *reinterpret_cast<const bf16x8*>(&Vw[32 + q][(hi ^ sx) * 8]);
      bf16x8 va11 = *reinterpret_cast<const bf16x8*>(&Vw[32 + q][((2 + hi) ^ sx) * 8]);
      O0 = __builtin_amdgcn_mfma_f32_32x32x16_bf16(va00, pf0.v, O0, 0, 0, 0);
      O0 = __builtin_amdgcn_mfma_f32_32x32x16_bf16(va01, pf1.v, O0, 0, 0, 0);
      O1 = __builtin_amdgcn_mfma_f32_32x32x16_bf16(va10, pf0.v, O1, 0, 0, 0);
      O1 = __builtin_amdgcn_mfma_f32_32x32x16_bf16(va11, pf1.v, O1, 0, 0, 0);
    }
  }
  float l_run = lacc + __shfl_xor(lacc, 32);

  // -------- merge the 4 waves -> block partial (fp32, no division) --------
  const int pidx = (bh * 32 + itile) * 2 + jh;
  float* prow_base = part + (size_t)pidx * 32 * 68;
  float (*Ow)[33] = reinterpret_cast<float(*)[33]>(smem[w]);   // overlays Vw
  if (hi == 0) { Mlds[w][q] = m_run; Llds[w][q] = l_run; }
#pragma unroll
  for (int r = 0; r < 16; ++r)
    Ow[q][(r & 3) + 8 * (r >> 2) + 4 * hi] = O0[r];
  __syncthreads();
  const int mi = t >> 3, dl = (t & 7) * 4;
  float m0v = Mlds[0][mi], m1v = Mlds[1][mi], m2v = Mlds[2][mi], m3v = Mlds[3][mi];
  float mm = fmaxf(fmaxf(m0v, m1v), fmaxf(m2v, m3v));
  float sc0 = fexp2(m0v - mm), sc1 = fexp2(m1v - mm);
  float sc2 = fexp2(m2v - mm), sc3 = fexp2(m3v - mm);
  float ll = Llds[0][mi] * sc0 + Llds[1][mi] * sc1 + Llds[2][mi] * sc2 + Llds[3][mi] * sc3;
  float* prow = prow_base + (size_t)mi * 68;
  {
    float(*O0p)[33] = reinterpret_cast<float(*)[33]>(smem[0]);
    float(*O1p)[33] = reinterpret_cast<float(*)[33]>(smem[1]);
    float(*O2p)[33] = reinterpret_cast<float(*)[33]>(smem[2]);
    float(*O3p)[33] = reinterpret_cast<float(*)[33]>(smem[3]);
    float4 o;
    o.x = O0p[mi][dl + 0] * sc0 + O1p[mi][dl + 0] * sc1 + O2p[mi][dl + 0] * sc2 + O3p[mi][dl + 0] * sc3;
    o.y = O0p[mi][dl + 1] * sc0 + O1p[mi][dl + 1] * sc1 + O2p[mi][dl + 1] * sc2 + O3p[mi][dl + 1] * sc3;
    o.z = O0p[mi][dl + 2] * sc0 + O1p[mi][dl + 2] * sc1 + O2p[mi][dl + 2] * sc2 + O3p[mi][dl + 2] * sc3;
    o.w = O0p[mi][dl + 3] * sc0 + O1p[mi][dl + 3] * sc1 + O2p[mi][dl + 3] * sc2 + O3p[mi][dl + 3] * sc3;
    *reinterpret_cast<float4*>(prow + dl) = o;
    if ((t & 7) == 0) { prow[64] = mm; prow[65] = ll; }
  }
  __syncthreads();
#pragma unroll
  for (int r = 0; r < 16; ++r)
    Ow[q][(r & 3) + 8 * (r >> 2) + 4 * hi] = O1[r];
  __syncthreads();
  {
    float(*O0p)[33] = reinterpret_cast<float(*)[33]>(smem[0]);
    float(*O1p)[33] = reinterpret_cast<float(*)[33]>(smem[1]);
    float(*O2p)[33] = reinterpret_cast<float(*)[33]>(smem[2]);
    float(*O3p)[33] = reinterpret_cast<float(*)[33]>(smem[3]);
    float4 o;
    o.x = O0p[mi][dl + 0] * sc0 + O1p[mi][dl + 0] * sc1 + O2p[mi][dl + 0] * sc2 + O3p[mi][dl + 0] * sc3;
    o.y = O0p[mi][dl + 1] * sc0 + O1p[mi][dl + 1] * sc1 + O2p[mi][dl + 1] * sc2 + O3p[mi][dl + 1] * sc3;
    o.z = O0p[mi][dl + 2] * sc0 + O1p[mi][dl + 2] * sc1 + O2p[mi][dl + 2] * sc2 + O3p[mi][dl + 2] * sc3;
    o.w = O0p[mi][dl + 3] * sc0 + O1p[mi][dl + 3] * sc1 + O2p[mi][dl + 3] * sc2 + O3p[mi][dl + 3] * sc3;
    *reinterpret_cast<float4*>(prow + 32 + dl) = o;
  }
}

// ---------------- merge the 2 j-split partials -> aout (bf16) ----------------
__global__ void k_fmerge(const float* __restrict__ part, __bf16* __restrict__ aout) {
  const int u = blockIdx.x;                      // 1024 = bh(32) x itile(32)
  const int bh = u >> 5, itile = u & 31;
  const int b = bh >> 4, h = bh & 15, iw = itile * 32;
  const int t = threadIdx.x;
  const int mi = t >> 3, d0 = (t & 7) * 8;
  const float* p0 = part + ((size_t)(u * 2 + 0) * 32 + mi) * 68;
  const float* p1 = part + ((size_t)(u * 2 + 1) * 32 + mi) * 68;
  float m0 = p0[64], l0 = p0[65], m1 = p1[64], l1 = p1[65];
  float mm = fmaxf(m0, m1);
  float sc0 = fexp2(m0 - mm), sc1 = fexp2(m1 - mm);
  float inv = 1.f / (l0 * sc0 + l1 * sc1);
  union { __bf16 hh[8]; uint4 u4; } pk;
#pragma unroll
  for (int e = 0; e < 8; ++e)
    pk.hh[e] = (__bf16)((p0[d0 + e] * sc0 + p1[d0 + e] * sc1) * inv);
  *reinterpret_cast<uint4*>(aout + ((size_t)(b * LATENT) + iw + mi) * DIMC + h * DHH + d0) = pk.u4;
}

// ---------------- host launcher ----------------
extern "C" void kernel_launch(void* const* d_in, const int* in_sizes, int n_in,
                              void* d_out, int out_size, void* d_ws, size_t ws_size,
                              hipStream_t stream) {
  const float* x = (const float*)d_in[0];
  const float* Wq = (const float*)d_in[1];
  const float* Wkv = (const float*)d_in[2];
  const float* Wo = (const float*)d_in[3];
  const float* bo = (const float*)d_in[4];
  const float* gamma = (const float*)d_in[5];
  const float* beta = (const float*)d_in[6];

  char* ws = (char*)d_ws;
  size_t o = 0;
  __bf16* x16 = (__bf16*)(ws + o);  o += (size_t)BATCH * SEQ * DIMC * 2;
  __bf16* wq16 = (__bf16*)(ws + o); o += (size_t)DIMC * DIMC * 2;
  __bf16* wkv16 = (__bf16*)(ws + o); o += (size_t)DIMC * DIMC * 2;
  __bf16* wo16 = (__bf16*)(ws + o); o += (size_t)DIMC * DIMC * 2;
  float2* cstab = (float2*)(ws + o); o += (size_t)SEQ * 32 * 8;
  __bf16* kvn = (__bf16*)(ws + o);  o += (size_t)BATCH * HEADS * SEQ * DHH * 2;
  __bf16* kvnT = (__bf16*)(ws + o); o += (size_t)BATCH * HEADS * SEQ * DHH * 2;
  __bf16* qb = (__bf16*)(ws + o);   o += (size_t)BATCH * HEADS * LATENT * DHH * 2;
  __bf16* aout = (__bf16*)(ws + o); o += (size_t)BATCH * LATENT * DIMC * 2;
  float* part = (float*)(ws + o);   o += (size_t)2048 * 32 * 68 * 4;

  k_prep<<<4096, 256, 0, stream>>>(x, Wq, Wkv, Wo, x16, wq16, wkv16, wo16, cstab);
  k_gemmqkv<<<640, 256, 0, stream>>>(x16, wkv16, wq16, kvn, kvnT, qb, gamma, beta, cstab);
  k_flash8<<<2048, 256, 0, stream>>>(qb, kvn, kvnT, part);
  k_fmerge<<<1024, 256, 0, stream>>>(part, aout);
  k_gemm<1><<<128, 256, 0, stream>>>(aout, wo16, (float*)d_out, bo, 2048, 1024, 1024);
}

// Round 12
// 159.462 us; speedup vs baseline: 1.1024x; 1.1024x over previous
//
#include <hip/hip_runtime.h>
#include <hip/hip_bf16.h>
#include <cstdint>

#define DIMC 1024
#define HEADS 16
#define DHH 64
#define SEQ 4096
#define LATENT 1024
#define HISTC 3072
#define BATCH 2

typedef __attribute__((ext_vector_type(8))) __bf16 bf16x8;
typedef __attribute__((ext_vector_type(4))) float f32x4;
typedef __attribute__((ext_vector_type(16))) float f32x16;

// ---------------- fused prep: x->bf16, 3 weights->bf16, RoPE cos/sin table ----
__global__ void k_prep(const float* __restrict__ x, const float* __restrict__ Wq,
                       const float* __restrict__ Wkv, const float* __restrict__ Wo,
                       __bf16* __restrict__ x16, __bf16* __restrict__ wq16,
                       __bf16* __restrict__ wkv16, __bf16* __restrict__ wo16,
                       float2* __restrict__ cs) {
  int bidx = blockIdx.x;
  if (bidx < 2048) {
    int base = bidx * 256 + threadIdx.x;
#pragma unroll
    for (int k = 0; k < 4; ++k) {
      int i = base + k * 524288;
      float4 v = reinterpret_cast<const float4*>(x)[i];
      union { __bf16 h[4]; uint64_t u; } p;
      p.h[0] = (__bf16)v.x; p.h[1] = (__bf16)v.y;
      p.h[2] = (__bf16)v.z; p.h[3] = (__bf16)v.w;
      reinterpret_cast<uint64_t*>(x16)[i] = p.u;
    }
  } else if (bidx < 3584) {
    int id = bidx - 2048;
    const float* src; __bf16* dst;
    if (id < 512) { src = Wq; dst = wq16; }
    else if (id < 1024) { src = Wkv; dst = wkv16; id -= 512; }
    else { src = Wo; dst = wo16; id -= 1024; }
#pragma unroll
    for (int k = 0; k < 2; ++k) {
      int idx = id * 512 + k * 256 + threadIdx.x;
      float4 v = reinterpret_cast<const float4*>(src)[idx];
      union { __bf16 h[4]; uint64_t u; } p;
      p.h[0] = (__bf16)v.x; p.h[1] = (__bf16)v.y;
      p.h[2] = (__bf16)v.z; p.h[3] = (__bf16)v.w;
      reinterpret_cast<uint64_t*>(dst)[idx] = p.u;
    }
  } else {
    int idx = (bidx - 3584) * 256 + threadIdx.x;   // 4096*32 entries
    int pos = idx >> 5, f = idx & 31;
    float invf = exp2f(-(float)f * 0.41524101186f);  // log2(10000)/32
    float s, c;
    sincosf((float)pos * invf, &s, &c);
    cs[idx] = make_float2(c, s);
  }
}

// ---------------- async global->LDS 16B ----------------
__device__ __forceinline__ void gload16(void* lds, const void* g) {
  __builtin_amdgcn_global_load_lds(
      (const __attribute__((address_space(1))) unsigned int*)g,
      (__attribute__((address_space(3))) unsigned int*)lds, 16, 0, 0);
}

// ---------------- plain GEMM (o-proj): C = A @ Bw^T + bias ----
template<int BIAS>
__launch_bounds__(256)
__global__ void k_gemm(const __bf16* __restrict__ A, const __bf16* __restrict__ Bw,
                       float* __restrict__ C, const float* __restrict__ bias,
                       int M, int N, int K) {
  __shared__ __align__(16) char lds[16384];
  const int t = threadIdx.x;
  const int l = t & 63, w = t >> 6;
  const int wr = w >> 1, wc = w & 1;
  const int mblocks = M >> 7;
  const int m0 = (blockIdx.x % mblocks) * 128, n0 = (blockIdx.x / mblocks) * 128;
  const int lrow = l & 15, lk = l >> 4;
  f32x4 acc[4][4] = {};

  for (int k0 = 0; k0 < K; k0 += 32) {
    if (k0) __syncthreads();
#pragma unroll
    for (int i = 0; i < 2; ++i) {
      int c = i * 256 + t;
      int row = c >> 2, kc = c & 3;
      gload16(lds + c * 16, A + (size_t)(m0 + row) * K + k0 + kc * 8);
      gload16(lds + 8192 + c * 16, Bw + (size_t)(n0 + row) * K + k0 + kc * 8);
    }
    __syncthreads();
    bf16x8 af[4], bfr[4];
#pragma unroll
    for (int m = 0; m < 4; ++m)
      af[m] = *reinterpret_cast<const bf16x8*>(lds + (wr * 64 + m * 16 + lrow) * 64 + lk * 16);
#pragma unroll
    for (int n = 0; n < 4; ++n)
      bfr[n] = *reinterpret_cast<const bf16x8*>(lds + 8192 + (wc * 64 + n * 16 + lrow) * 64 + lk * 16);
#pragma unroll
    for (int m = 0; m < 4; ++m)
#pragma unroll
      for (int n = 0; n < 4; ++n)
        acc[m][n] = __builtin_amdgcn_mfma_f32_16x16x32_bf16(af[m], bfr[n], acc[m][n], 0, 0, 0);
  }

#pragma unroll
  for (int m = 0; m < 4; ++m)
#pragma unroll
    for (int n = 0; n < 4; ++n)
#pragma unroll
      for (int r = 0; r < 4; ++r) {
        int row = m0 + wr * 64 + m * 16 + (l >> 4) * 4 + r;
        int col = n0 + wc * 64 + n * 16 + (l & 15);
        float v = acc[m][n][r];
        if (BIAS) v += bias[col];
        C[(size_t)row * N + col] = v;
      }
}

// ---------------- fused QKV GEMM: kv-proj(+RoPE+LN) and q-proj(+RoPE+scale) ----
__launch_bounds__(256)
__global__ void k_gemmqkv(const __bf16* __restrict__ x16,
                          const __bf16* __restrict__ wkv16,
                          const __bf16* __restrict__ wq16,
                          __bf16* __restrict__ kvn, __bf16* __restrict__ kvnT,
                          __bf16* __restrict__ qb,
                          const float* __restrict__ gamma,
                          const float* __restrict__ beta,
                          const float2* __restrict__ cstab) {
  __shared__ __align__(16) char lds[16384];
  const int t = threadIdx.x, l = t & 63, w = t >> 6;
  const int wr = w >> 1, wc = w & 1;
  const int by = blockIdx.x % 80;
  const bool isq = by >= 64;
  const int m0 = (isq ? (by - 64) : by) * 128;
  const int n0 = (blockIdx.x / 80) * 128;
  const __bf16* Bw = isq ? wq16 : wkv16;
  const int lrow = l & 15, lk = l >> 4;
  f32x4 acc[4][4] = {};

  for (int k0 = 0; k0 < 1024; k0 += 32) {
    if (k0) __syncthreads();
#pragma unroll
    for (int i = 0; i < 2; ++i) {
      int c = i * 256 + t;
      int row = c >> 2, kc = c & 3;
      int mi = m0 + row;
      if (isq) mi += HISTC + (mi >> 10) * HISTC;
      gload16(lds + c * 16, x16 + (size_t)mi * 1024 + k0 + kc * 8);
      gload16(lds + 8192 + c * 16, Bw + (size_t)(n0 + row) * 1024 + k0 + kc * 8);
    }
    __syncthreads();
    bf16x8 af[4], bfr[4];
#pragma unroll
    for (int m = 0; m < 4; ++m)
      af[m] = *reinterpret_cast<const bf16x8*>(lds + (wr * 64 + m * 16 + lrow) * 64 + lk * 16);
#pragma unroll
    for (int n = 0; n < 4; ++n)
      bfr[n] = *reinterpret_cast<const bf16x8*>(lds + 8192 + (wc * 64 + n * 16 + lrow) * 64 + lk * 16);
#pragma unroll
    for (int m = 0; m < 4; ++m)
#pragma unroll
      for (int n = 0; n < 4; ++n)
        acc[m][n] = __builtin_amdgcn_mfma_f32_16x16x32_bf16(af[m], bfr[n], acc[m][n], 0, 0, 0);
  }

  // ---- RoPE in place via table ----
#pragma unroll
  for (int m = 0; m < 4; ++m)
#pragma unroll
    for (int r = 0; r < 4; ++r) {
      int rl = wr * 64 + m * 16 + lk * 4 + r;
      int pos = isq ? (HISTC + ((m0 + rl) & 1023)) : ((m0 + rl) & 4095);
      float2 cs0 = cstab[pos * 32 + lrow];
      float2 cs1 = cstab[pos * 32 + 16 + lrow];
      float a0 = acc[m][0][r], a2 = acc[m][2][r];
      acc[m][0][r] = a0 * cs0.x - a2 * cs0.y;
      acc[m][2][r] = a2 * cs0.x + a0 * cs0.y;
      float a1 = acc[m][1][r], a3 = acc[m][3][r];
      acc[m][1][r] = a1 * cs1.x - a3 * cs1.y;
      acc[m][3][r] = a3 * cs1.x + a1 * cs1.y;
    }

  const int h = (n0 + wc * 64) >> 6;
  if (!isq) {
    float g4[4], b4[4];
#pragma unroll
    for (int n = 0; n < 4; ++n) { g4[n] = gamma[n * 16 + lrow]; b4[n] = beta[n * 16 + lrow]; }
#pragma unroll
    for (int m = 0; m < 4; ++m)
#pragma unroll
      for (int r = 0; r < 4; ++r) {
        float s1 = acc[m][0][r] + acc[m][1][r] + acc[m][2][r] + acc[m][3][r];
        float s2 = acc[m][0][r] * acc[m][0][r] + acc[m][1][r] * acc[m][1][r] +
                   acc[m][2][r] * acc[m][2][r] + acc[m][3][r] * acc[m][3][r];
#pragma unroll
        for (int mk = 1; mk < 16; mk <<= 1) {
          s1 += __shfl_xor(s1, mk);
          s2 += __shfl_xor(s2, mk);
        }
        float mu = s1 * 0.015625f;
        float var = s2 * 0.015625f - mu * mu;
        float inv = rsqrtf(var + 1e-5f);
#pragma unroll
        for (int n = 0; n < 4; ++n)
          acc[m][n][r] = (acc[m][n][r] - mu) * inv * g4[n] + b4[n];
      }
    const size_t hb = (size_t)((m0 >> 12) * HEADS + h);
#pragma unroll
    for (int m = 0; m < 4; ++m)
#pragma unroll
      for (int r = 0; r < 4; ++r) {
        int pos = (m0 + wr * 64 + m * 16 + lk * 4 + r) & 4095;
#pragma unroll
        for (int n = 0; n < 4; ++n)
          kvn[(hb * SEQ + pos) * DHH + n * 16 + lrow] = (__bf16)acc[m][n][r];
      }
#pragma unroll
    for (int m = 0; m < 4; ++m) {
      int pos0 = (m0 + wr * 64 + m * 16 + lk * 4) & 4095;
      int sp = (pos0 & ~12) | ((pos0 & 4) << 1) | ((pos0 & 8) >> 1);
#pragma unroll
      for (int n = 0; n < 4; ++n) {
        union { __bf16 hh[4]; uint64_t u; } pk;
#pragma unroll
        for (int r = 0; r < 4; ++r) pk.hh[r] = (__bf16)acc[m][n][r];
        *reinterpret_cast<uint64_t*>(kvnT + (hb * DHH + n * 16 + lrow) * SEQ + sp) = pk.u;
      }
    }
  } else {
    const size_t hb = (size_t)((m0 >> 10) * HEADS + h);
#pragma unroll
    for (int m = 0; m < 4; ++m)
#pragma unroll
      for (int r = 0; r < 4; ++r) {
        int qi = (m0 + wr * 64 + m * 16 + lk * 4 + r) & 1023;
#pragma unroll
        for (int n = 0; n < 4; ++n)
          qb[(hb * LATENT + qi) * DHH + n * 16 + lrow] =
              (__bf16)(acc[m][n][r] * 0.18033688011112042f);
      }
  }
}

// ---------------- helpers for flash ----------------
__device__ __forceinline__ float fexp2(float x) {
#if __has_builtin(__builtin_amdgcn_exp2f)
  return __builtin_amdgcn_exp2f(x);
#else
  return exp2f(x);
#endif
}

__device__ __forceinline__ unsigned pk2(float a, float b) {
  union { __bf16 h[2]; unsigned u; } x;
  x.h[0] = (__bf16)a; x.h[1] = (__bf16)b;
  return x.u;
}

// ---------------- flash attention v9 ----------------
// QBLK=64: block owns an itile PAIR (64 q rows); each wave holds 2 Q sets and
// 2 accumulator sets so every K/V tile load feeds 2x MFMA work -> K/V L2
// traffic halved (the hypothesized binding resource). Grid 512, XCD-pinned,
// pair-flip for CU work balance. Per-subtile math identical to flash5/7.
__launch_bounds__(256)
__global__ void k_flash9(const __bf16* __restrict__ qb, const __bf16* __restrict__ kvn,
                         const __bf16* __restrict__ kvnT, __bf16* __restrict__ aout) {
  const int bid = blockIdx.x;                  // [0,512)
  const int grp = bid >> 7;                    // [0,4)
  const int bh = (bid & 7) + 8 * grp;          // [0,32)
  int itp = (bid >> 3) & 15;
  if (grp >= 2) itp = 15 - itp;                // CU work balance
  const int h = bh & 15, b = bh >> 4;
  const int t = threadIdx.x, l = t & 63, w = t >> 6;
  const int q = l & 31, hi = l >> 5;
  const int iw0 = itp * 64;
  const int i0 = iw0 + q, i1 = iw0 + 32 + q;
  const __bf16* qbase = qb + ((size_t)(b * HEADS + h) * LATENT + iw0) * DHH;
  const __bf16* kbase = kvn + (size_t)(b * HEADS + h) * SEQ * DHH;
  const __bf16* vbase = kvnT + (size_t)(b * HEADS + h) * DHH * SEQ;

  __shared__ __align__(16) char smem[4][4352];   // per-wave: V [64][32] | merge Ow [32][33]
  __shared__ float Mlds[4][32];
  __shared__ float Llds[4][32];
  __bf16 (*Vw)[32] = reinterpret_cast<__bf16(*)[32]>(smem[w]);

  bf16x8 qf0[4], qf1[4];
#pragma unroll
  for (int c = 0; c < 4; ++c) {
    qf0[c] = *reinterpret_cast<const bf16x8*>(qbase + (size_t)q * DHH + c * 16 + hi * 8);
    qf1[c] = *reinterpret_cast<const bf16x8*>(qbase + (size_t)(32 + q) * DHH + c * 16 + hi * 8);
  }

  const f32x16 Z = {};
  f32x16 O00 = {}, O01 = {}, O10 = {}, O11 = {};
  float m0r = -INFINITY, lacc0 = 0.f;
  float m1r = -INFINITY, lacc1 = 0.f;

  const int nt = 2 * itp + 98;                 // 32-key tiles (exact: (iw0+64+HISTC)/32)
  const int t0 = (nt * w) >> 2, t1 = (nt * (w + 1)) >> 2;

  const int srow = l >> 2, scol = l & 3;
  const int wchunk = (scol ^ (srow & 3)) * 8;  // XOR-swizzled 16B chunk slot
  const int sx = q & 3;
  bf16x8 vreg[4], kreg[4];
#pragma unroll
  for (int ii = 0; ii < 4; ++ii)
    vreg[ii] = *reinterpret_cast<const bf16x8*>(
        vbase + (size_t)(ii * 16 + srow) * SEQ + t0 * 32 + scol * 8);
#pragma unroll
  for (int c = 0; c < 4; ++c)
    kreg[c] = *reinterpret_cast<const bf16x8*>(
        kbase + (size_t)(t0 * 32 + q) * DHH + c * 16 + hi * 8);

  for (int tt = t0; tt < t1; ++tt) {
    const int j0 = tt * 32;
    // QK^T for both q-subtiles (kreg consumed before prefetch)
    f32x16 S0 = __builtin_amdgcn_mfma_f32_32x32x16_bf16(kreg[0], qf0[0], Z, 0, 0, 0);
    S0 = __builtin_amdgcn_mfma_f32_32x32x16_bf16(kreg[1], qf0[1], S0, 0, 0, 0);
    S0 = __builtin_amdgcn_mfma_f32_32x32x16_bf16(kreg[2], qf0[2], S0, 0, 0, 0);
    S0 = __builtin_amdgcn_mfma_f32_32x32x16_bf16(kreg[3], qf0[3], S0, 0, 0, 0);
    f32x16 S1 = __builtin_amdgcn_mfma_f32_32x32x16_bf16(kreg[0], qf1[0], Z, 0, 0, 0);
    S1 = __builtin_amdgcn_mfma_f32_32x32x16_bf16(kreg[1], qf1[1], S1, 0, 0, 0);
    S1 = __builtin_amdgcn_mfma_f32_32x32x16_bf16(kreg[2], qf1[2], S1, 0, 0, 0);
    S1 = __builtin_amdgcn_mfma_f32_32x32x16_bf16(kreg[3], qf1[3], S1, 0, 0, 0);
    // commit V(tt) into swizzled LDS (wave-private)
#pragma unroll
    for (int ii = 0; ii < 4; ++ii)
      *reinterpret_cast<bf16x8*>(&Vw[ii * 16 + srow][wchunk]) = vreg[ii];
    // clamped prefetch of tile tt+1
    const int tn = (tt + 1 < t1) ? tt + 1 : tt;
#pragma unroll
    for (int ii = 0; ii < 4; ++ii)
      vreg[ii] = *reinterpret_cast<const bf16x8*>(
          vbase + (size_t)(ii * 16 + srow) * SEQ + tn * 32 + scol * 8);
#pragma unroll
    for (int c = 0; c < 4; ++c)
      kreg[c] = *reinterpret_cast<const bf16x8*>(
          kbase + (size_t)(tn * 32 + q) * DHH + c * 16 + hi * 8);
    // V frags (read once, feed both subtiles' PV)
    bf16x8 va00 = *reinterpret_cast<const bf16x8*>(&Vw[q][(hi ^ sx) * 8]);
    bf16x8 va01 = *reinterpret_cast<const bf16x8*>(&Vw[q][((2 + hi) ^ sx) * 8]);
    bf16x8 va10 = *reinterpret_cast<const bf16x8*>(&Vw[32 + q][(hi ^ sx) * 8]);
    bf16x8 va11 = *reinterpret_cast<const bf16x8*>(&Vw[32 + q][((2 + hi) ^ sx) * 8]);
    // ---------------- subtile 0 ----------------
    if (j0 + 31 > i0 + HISTC - 31 + 31) {      // j0+31 > iw0+HISTC
#pragma unroll
      for (int r = 0; r < 16; ++r) {
        int j = j0 + (r & 3) + 8 * (r >> 2) + 4 * hi;
        if (j > i0 + HISTC) S0[r] = -1e30f;
      }
    }
    {
      float u1 = fmaxf(fmaxf(S0[0], S0[1]), S0[2]);
      float u2 = fmaxf(fmaxf(S0[3], S0[4]), S0[5]);
      float u3 = fmaxf(fmaxf(S0[6], S0[7]), S0[8]);
      float u4 = fmaxf(fmaxf(S0[9], S0[10]), S0[11]);
      float u5 = fmaxf(fmaxf(S0[12], S0[13]), S0[14]);
      float pm = fmaxf(fmaxf(fmaxf(u1, u2), u3), fmaxf(fmaxf(u4, u5), S0[15]));
      if (__any(pm > m0r + 8.0f)) {
        pm = fmaxf(pm, __shfl_xor(pm, 32));
        float mn = fmaxf(m0r, pm);
        float sc = fexp2(m0r - mn);
        m0r = mn;
        lacc0 *= sc;
#pragma unroll
        for (int r = 0; r < 16; ++r) { O00[r] *= sc; O01[r] *= sc; }
      }
      float p[16];
#pragma unroll
      for (int r = 0; r < 16; ++r) p[r] = fexp2(S0[r] - m0r);
      float s8[8];
#pragma unroll
      for (int r = 0; r < 8; ++r) s8[r] = p[r] + p[r + 8];
      lacc0 += ((s8[0] + s8[4]) + (s8[1] + s8[5])) + ((s8[2] + s8[6]) + (s8[3] + s8[7]));
      union { unsigned u[4]; bf16x8 v; } pf0, pf1;
      pf0.u[0] = pk2(p[0], p[1]);   pf0.u[1] = pk2(p[2], p[3]);
      pf0.u[2] = pk2(p[4], p[5]);   pf0.u[3] = pk2(p[6], p[7]);
      pf1.u[0] = pk2(p[8], p[9]);   pf1.u[1] = pk2(p[10], p[11]);
      pf1.u[2] = pk2(p[12], p[13]); pf1.u[3] = pk2(p[14], p[15]);
      O00 = __builtin_amdgcn_mfma_f32_32x32x16_bf16(va00, pf0.v, O00, 0, 0, 0);
      O00 = __builtin_amdgcn_mfma_f32_32x32x16_bf16(va01, pf1.v, O00, 0, 0, 0);
      O01 = __builtin_amdgcn_mfma_f32_32x32x16_bf16(va10, pf0.v, O01, 0, 0, 0);
      O01 = __builtin_amdgcn_mfma_f32_32x32x16_bf16(va11, pf1.v, O01, 0, 0, 0);
    }
    // ---------------- subtile 1 ----------------
    if (j0 + 31 > iw0 + 32 + HISTC) {
#pragma unroll
      for (int r = 0; r < 16; ++r) {
        int j = j0 + (r & 3) + 8 * (r >> 2) + 4 * hi;
        if (j > i1 + HISTC) S1[r] = -1e30f;
      }
    }
    {
      float u1 = fmaxf(fmaxf(S1[0], S1[1]), S1[2]);
      float u2 = fmaxf(fmaxf(S1[3], S1[4]), S1[5]);
      float u3 = fmaxf(fmaxf(S1[6], S1[7]), S1[8]);
      float u4 = fmaxf(fmaxf(S1[9], S1[10]), S1[11]);
      float u5 = fmaxf(fmaxf(S1[12], S1[13]), S1[14]);
      float pm = fmaxf(fmaxf(fmaxf(u1, u2), u3), fmaxf(fmaxf(u4, u5), S1[15]));
      if (__any(pm > m1r + 8.0f)) {
        pm = fmaxf(pm, __shfl_xor(pm, 32));
        float mn = fmaxf(m1r, pm);
        float sc = fexp2(m1r - mn);
        m1r = mn;
        lacc1 *= sc;
#pragma unroll
        for (int r = 0; r < 16; ++r) { O10[r] *= sc; O11[r] *= sc; }
      }
      float p[16];
#pragma unroll
      for (int r = 0; r < 16; ++r) p[r] = fexp2(S1[r] - m1r);
      float s8[8];
#pragma unroll
      for (int r = 0; r < 8; ++r) s8[r] = p[r] + p[r + 8];
      lacc1 += ((s8[0] + s8[4]) + (s8[1] + s8[5])) + ((s8[2] + s8[6]) + (s8[3] + s8[7]));
      union { unsigned u[4]; bf16x8 v; } pf0, pf1;
      pf0.u[0] = pk2(p[0], p[1]);   pf0.u[1] = pk2(p[2], p[3]);
      pf0.u[2] = pk2(p[4], p[5]);   pf0.u[3] = pk2(p[6], p[7]);
      pf1.u[0] = pk2(p[8], p[9]);   pf1.u[1] = pk2(p[10], p[11]);
      pf1.u[2] = pk2(p[12], p[13]); pf1.u[3] = pk2(p[14], p[15]);
      O10 = __builtin_amdgcn_mfma_f32_32x32x16_bf16(va00, pf0.v, O10, 0, 0, 0);
      O10 = __builtin_amdgcn_mfma_f32_32x32x16_bf16(va01, pf1.v, O10, 0, 0, 0);
      O11 = __builtin_amdgcn_mfma_f32_32x32x16_bf16(va10, pf0.v, O11, 0, 0, 0);
      O11 = __builtin_amdgcn_mfma_f32_32x32x16_bf16(va11, pf1.v, O11, 0, 0, 0);
    }
  }
  float l0r = lacc0 + __shfl_xor(lacc0, 32);
  float l1r = lacc1 + __shfl_xor(lacc1, 32);

  // -------- merge 4 waves, two subtiles, chunked over d --------
  float (*Ow)[33] = reinterpret_cast<float(*)[33]>(smem[w]);   // overlays Vw
  const int mi = t >> 3, dl = (t & 7) * 4;
  // ---- subtile 0 ----
  if (hi == 0) { Mlds[w][q] = m0r; Llds[w][q] = l0r; }
#pragma unroll
  for (int r = 0; r < 16; ++r)
    Ow[q][(r & 3) + 8 * (r >> 2) + 4 * hi] = O00[r];
  __syncthreads();
  float m0v = Mlds[0][mi], m1v = Mlds[1][mi], m2v = Mlds[2][mi], m3v = Mlds[3][mi];
  float mm = fmaxf(fmaxf(m0v, m1v), fmaxf(m2v, m3v));
  float sc0 = fexp2(m0v - mm), sc1 = fexp2(m1v - mm);
  float sc2 = fexp2(m2v - mm), sc3 = fexp2(m3v - mm);
  float ll = Llds[0][mi] * sc0 + Llds[1][mi] * sc1 + Llds[2][mi] * sc2 + Llds[3][mi] * sc3;
  float inv = 1.f / ll;
  {
    float(*A0)[33] = reinterpret_cast<float(*)[33]>(smem[0]);
    float(*A1)[33] = reinterpret_cast<float(*)[33]>(smem[1]);
    float(*A2)[33] = reinterpret_cast<float(*)[33]>(smem[2]);
    float(*A3)[33] = reinterpret_cast<float(*)[33]>(smem[3]);
    __bf16* orow = aout + ((size_t)(b * LATENT) + iw0 + mi) * DIMC + h * DHH;
    union { __bf16 hh[4]; uint2 u2; } pkv;
#pragma unroll
    for (int e = 0; e < 4; ++e) {
      float o = A0[mi][dl + e] * sc0 + A1[mi][dl + e] * sc1 +
                A2[mi][dl + e] * sc2 + A3[mi][dl + e] * sc3;
      pkv.hh[e] = (__bf16)(o * inv);
    }
    *reinterpret_cast<uint2*>(orow + dl) = pkv.u2;
  }
  __syncthreads();
#pragma unroll
  for (int r = 0; r < 16; ++r)
    Ow[q][(r & 3) + 8 * (r >> 2) + 4 * hi] = O01[r];
  __syncthreads();
  {
    float(*A0)[33] = reinterpret_cast<float(*)[33]>(smem[0]);
    float(*A1)[33] = reinterpret_cast<float(*)[33]>(smem[1]);
    float(*A2)[33] = reinterpret_cast<float(*)[33]>(smem[2]);
    float(*A3)[33] = reinterpret_cast<float(*)[33]>(smem[3]);
    __bf16* orow = aout + ((size_t)(b * LATENT) + iw0 + mi) * DIMC + h * DHH;
    union { __bf16 hh[4]; uint2 u2; } pkv;
#pragma unroll
    for (int e = 0; e < 4; ++e) {
      float o = A0[mi][dl + e] * sc0 + A1[mi][dl + e] * sc1 +
                A2[mi][dl + e] * sc2 + A3[mi][dl + e] * sc3;
      pkv.hh[e] = (__bf16)(o * inv);
    }
    *reinterpret_cast<uint2*>(orow + 32 + dl) = pkv.u2;
  }
  __syncthreads();
  // ---- subtile 1 ----
  if (hi == 0) { Mlds[w][q] = m1r; Llds[w][q] = l1r; }
#pragma unroll
  for (int r = 0; r < 16; ++r)
    Ow[q][(r & 3) + 8 * (r >> 2) + 4 * hi] = O10[r];
  __syncthreads();
  m0v = Mlds[0][mi]; m1v = Mlds[1][mi]; m2v = Mlds[2][mi]; m3v = Mlds[3][mi];
  mm = fmaxf(fmaxf(m0v, m1v), fmaxf(m2v, m3v));
  sc0 = fexp2(m0v - mm); sc1 = fexp2(m1v - mm);
  sc2 = fexp2(m2v - mm); sc3 = fexp2(m3v - mm);
  ll = Llds[0][mi] * sc0 + Llds[1][mi] * sc1 + Llds[2][mi] * sc2 + Llds[3][mi] * sc3;
  inv = 1.f / ll;
  {
    float(*A0)[33] = reinterpret_cast<float(*)[33]>(smem[0]);
    float(*A1)[33] = reinterpret_cast<float(*)[33]>(smem[1]);
    float(*A2)[33] = reinterpret_cast<float(*)[33]>(smem[2]);
    float(*A3)[33] = reinterpret_cast<float(*)[33]>(smem[3]);
    __bf16* orow = aout + ((size_t)(b * LATENT) + iw0 + 32 + mi) * DIMC + h * DHH;
    union { __bf16 hh[4]; uint2 u2; } pkv;
#pragma unroll
    for (int e = 0; e < 4; ++e) {
      float o = A0[mi][dl + e] * sc0 + A1[mi][dl + e] * sc1 +
                A2[mi][dl + e] * sc2 + A3[mi][dl + e] * sc3;
      pkv.hh[e] = (__bf16)(o * inv);
    }
    *reinterpret_cast<uint2*>(orow + dl) = pkv.u2;
  }
  __syncthreads();
#pragma unroll
  for (int r = 0; r < 16; ++r)
    Ow[q][(r & 3) + 8 * (r >> 2) + 4 * hi] = O11[r];
  __syncthreads();
  {
    float(*A0)[33] = reinterpret_cast<float(*)[33]>(smem[0]);
    float(*A1)[33] = reinterpret_cast<float(*)[33]>(smem[1]);
    float(*A2)[33] = reinterpret_cast<float(*)[33]>(smem[2]);
    float(*A3)[33] = reinterpret_cast<float(*)[33]>(smem[3]);
    __bf16* orow = aout + ((size_t)(b * LATENT) + iw0 + 32 + mi) * DIMC + h * DHH;
    union { __bf16 hh[4]; uint2 u2; } pkv;
#pragma unroll
    for (int e = 0; e < 4; ++e) {
      float o = A0[mi][dl + e] * sc0 + A1[mi][dl + e] * sc1 +
                A2[mi][dl + e] * sc2 + A3[mi][dl + e] * sc3;
      pkv.hh[e] = (__bf16)(o * inv);
    }
    *reinterpret_cast<uint2*>(orow + 32 + dl) = pkv.u2;
  }
}

// ---------------- host launcher ----------------
extern "C" void kernel_launch(void* const* d_in, const int* in_sizes, int n_in,
                              void* d_out, int out_size, void* d_ws, size_t ws_size,
                              hipStream_t stream) {
  const float* x = (const float*)d_in[0];
  const float* Wq = (const float*)d_in[1];
  const float* Wkv = (const float*)d_in[2];
  const float* Wo = (const float*)d_in[3];
  const float* bo = (const float*)d_in[4];
  const float* gamma = (const float*)d_in[5];
  const float* beta = (const float*)d_in[6];

  char* ws = (char*)d_ws;
  size_t o = 0;
  __bf16* x16 = (__bf16*)(ws + o);  o += (size_t)BATCH * SEQ * DIMC * 2;
  __bf16* wq16 = (__bf16*)(ws + o); o += (size_t)DIMC * DIMC * 2;
  __bf16* wkv16 = (__bf16*)(ws + o); o += (size_t)DIMC * DIMC * 2;
  __bf16* wo16 = (__bf16*)(ws + o); o += (size_t)DIMC * DIMC * 2;
  float2* cstab = (float2*)(ws + o); o += (size_t)SEQ * 32 * 8;
  __bf16* kvn = (__bf16*)(ws + o);  o += (size_t)BATCH * HEADS * SEQ * DHH * 2;
  __bf16* kvnT = (__bf16*)(ws + o); o += (size_t)BATCH * HEADS * SEQ * DHH * 2;
  __bf16* qb = (__bf16*)(ws + o);   o += (size_t)BATCH * HEADS * LATENT * DHH * 2;
  __bf16* aout = (__bf16*)(ws + o); o += (size_t)BATCH * LATENT * DIMC * 2;

  k_prep<<<4096, 256, 0, stream>>>(x, Wq, Wkv, Wo, x16, wq16, wkv16, wo16, cstab);
  k_gemmqkv<<<640, 256, 0, stream>>>(x16, wkv16, wq16, kvn, kvnT, qb, gamma, beta, cstab);
  k_flash9<<<512, 256, 0, stream>>>(qb, kvn, kvnT, aout);
  k_gemm<1><<<128, 256, 0, stream>>>(aout, wo16, (float*)d_out, bo, 2048, 1024, 1024);
}

// Round 13
// 157.287 us; speedup vs baseline: 1.1177x; 1.0138x over previous
//
#include <hip/hip_runtime.h>
#include <hip/hip_bf16.h>
#include <cstdint>

#define DIMC 1024
#define HEADS 16
#define DHH 64
#define SEQ 4096
#define LATENT 1024
#define HISTC 3072
#define BATCH 2

typedef __attribute__((ext_vector_type(8))) __bf16 bf16x8;
typedef __attribute__((ext_vector_type(4))) float f32x4;
typedef __attribute__((ext_vector_type(16))) float f32x16;

// ---------------- fused prep: x->bf16, 3 weights->bf16, RoPE cos/sin table ----
__global__ void k_prep(const float* __restrict__ x, const float* __restrict__ Wq,
                       const float* __restrict__ Wkv, const float* __restrict__ Wo,
                       __bf16* __restrict__ x16, __bf16* __restrict__ wq16,
                       __bf16* __restrict__ wkv16, __bf16* __restrict__ wo16,
                       float2* __restrict__ cs) {
  int bidx = blockIdx.x;
  if (bidx < 2048) {
    int base = bidx * 256 + threadIdx.x;
#pragma unroll
    for (int k = 0; k < 4; ++k) {
      int i = base + k * 524288;
      float4 v = reinterpret_cast<const float4*>(x)[i];
      union { __bf16 h[4]; uint64_t u; } p;
      p.h[0] = (__bf16)v.x; p.h[1] = (__bf16)v.y;
      p.h[2] = (__bf16)v.z; p.h[3] = (__bf16)v.w;
      reinterpret_cast<uint64_t*>(x16)[i] = p.u;
    }
  } else if (bidx < 3584) {
    int id = bidx - 2048;
    const float* src; __bf16* dst;
    if (id < 512) { src = Wq; dst = wq16; }
    else if (id < 1024) { src = Wkv; dst = wkv16; id -= 512; }
    else { src = Wo; dst = wo16; id -= 1024; }
#pragma unroll
    for (int k = 0; k < 2; ++k) {
      int idx = id * 512 + k * 256 + threadIdx.x;
      float4 v = reinterpret_cast<const float4*>(src)[idx];
      union { __bf16 h[4]; uint64_t u; } p;
      p.h[0] = (__bf16)v.x; p.h[1] = (__bf16)v.y;
      p.h[2] = (__bf16)v.z; p.h[3] = (__bf16)v.w;
      reinterpret_cast<uint64_t*>(dst)[idx] = p.u;
    }
  } else {
    int idx = (bidx - 3584) * 256 + threadIdx.x;   // 4096*32 entries
    int pos = idx >> 5, f = idx & 31;
    float invf = exp2f(-(float)f * 0.41524101186f);  // log2(10000)/32
    float s, c;
    sincosf((float)pos * invf, &s, &c);
    cs[idx] = make_float2(c, s);
  }
}

// ---------------- async global->LDS 16B ----------------
__device__ __forceinline__ void gload16(void* lds, const void* g) {
  __builtin_amdgcn_global_load_lds(
      (const __attribute__((address_space(1))) unsigned int*)g,
      (__attribute__((address_space(3))) unsigned int*)lds, 16, 0, 0);
}

// ---------------- plain GEMM (o-proj): C = A @ Bw^T + bias ----
template<int BIAS>
__launch_bounds__(256)
__global__ void k_gemm(const __bf16* __restrict__ A, const __bf16* __restrict__ Bw,
                       float* __restrict__ C, const float* __restrict__ bias,
                       int M, int N, int K) {
  __shared__ __align__(16) char lds[16384];
  const int t = threadIdx.x;
  const int l = t & 63, w = t >> 6;
  const int wr = w >> 1, wc = w & 1;
  const int mblocks = M >> 7;
  const int m0 = (blockIdx.x % mblocks) * 128, n0 = (blockIdx.x / mblocks) * 128;
  const int lrow = l & 15, lk = l >> 4;
  f32x4 acc[4][4] = {};

  for (int k0 = 0; k0 < K; k0 += 32) {
    if (k0) __syncthreads();
#pragma unroll
    for (int i = 0; i < 2; ++i) {
      int c = i * 256 + t;
      int row = c >> 2, kc = c & 3;
      gload16(lds + c * 16, A + (size_t)(m0 + row) * K + k0 + kc * 8);
      gload16(lds + 8192 + c * 16, Bw + (size_t)(n0 + row) * K + k0 + kc * 8);
    }
    __syncthreads();
    bf16x8 af[4], bfr[4];
#pragma unroll
    for (int m = 0; m < 4; ++m)
      af[m] = *reinterpret_cast<const bf16x8*>(lds + (wr * 64 + m * 16 + lrow) * 64 + lk * 16);
#pragma unroll
    for (int n = 0; n < 4; ++n)
      bfr[n] = *reinterpret_cast<const bf16x8*>(lds + 8192 + (wc * 64 + n * 16 + lrow) * 64 + lk * 16);
#pragma unroll
    for (int m = 0; m < 4; ++m)
#pragma unroll
      for (int n = 0; n < 4; ++n)
        acc[m][n] = __builtin_amdgcn_mfma_f32_16x16x32_bf16(af[m], bfr[n], acc[m][n], 0, 0, 0);
  }

#pragma unroll
  for (int m = 0; m < 4; ++m)
#pragma unroll
    for (int n = 0; n < 4; ++n)
#pragma unroll
      for (int r = 0; r < 4; ++r) {
        int row = m0 + wr * 64 + m * 16 + (l >> 4) * 4 + r;
        int col = n0 + wc * 64 + n * 16 + (l & 15);
        float v = acc[m][n][r];
        if (BIAS) v += bias[col];
        C[(size_t)row * N + col] = v;
      }
}

// ---------------- fused QKV GEMM: kv-proj(+RoPE+LN) and q-proj(+RoPE+scale) ----
__launch_bounds__(256)
__global__ void k_gemmqkv(const __bf16* __restrict__ x16,
                          const __bf16* __restrict__ wkv16,
                          const __bf16* __restrict__ wq16,
                          __bf16* __restrict__ kvn, __bf16* __restrict__ kvnT,
                          __bf16* __restrict__ qb,
                          const float* __restrict__ gamma,
                          const float* __restrict__ beta,
                          const float2* __restrict__ cstab) {
  __shared__ __align__(16) char lds[16384];
  const int t = threadIdx.x, l = t & 63, w = t >> 6;
  const int wr = w >> 1, wc = w & 1;
  const int by = blockIdx.x % 80;
  const bool isq = by >= 64;
  const int m0 = (isq ? (by - 64) : by) * 128;
  const int n0 = (blockIdx.x / 80) * 128;
  const __bf16* Bw = isq ? wq16 : wkv16;
  const int lrow = l & 15, lk = l >> 4;
  f32x4 acc[4][4] = {};

  for (int k0 = 0; k0 < 1024; k0 += 32) {
    if (k0) __syncthreads();
#pragma unroll
    for (int i = 0; i < 2; ++i) {
      int c = i * 256 + t;
      int row = c >> 2, kc = c & 3;
      int mi = m0 + row;
      if (isq) mi += HISTC + (mi >> 10) * HISTC;
      gload16(lds + c * 16, x16 + (size_t)mi * 1024 + k0 + kc * 8);
      gload16(lds + 8192 + c * 16, Bw + (size_t)(n0 + row) * 1024 + k0 + kc * 8);
    }
    __syncthreads();
    bf16x8 af[4], bfr[4];
#pragma unroll
    for (int m = 0; m < 4; ++m)
      af[m] = *reinterpret_cast<const bf16x8*>(lds + (wr * 64 + m * 16 + lrow) * 64 + lk * 16);
#pragma unroll
    for (int n = 0; n < 4; ++n)
      bfr[n] = *reinterpret_cast<const bf16x8*>(lds + 8192 + (wc * 64 + n * 16 + lrow) * 64 + lk * 16);
#pragma unroll
    for (int m = 0; m < 4; ++m)
#pragma unroll
      for (int n = 0; n < 4; ++n)
        acc[m][n] = __builtin_amdgcn_mfma_f32_16x16x32_bf16(af[m], bfr[n], acc[m][n], 0, 0, 0);
  }

  // ---- RoPE in place via table ----
#pragma unroll
  for (int m = 0; m < 4; ++m)
#pragma unroll
    for (int r = 0; r < 4; ++r) {
      int rl = wr * 64 + m * 16 + lk * 4 + r;
      int pos = isq ? (HISTC + ((m0 + rl) & 1023)) : ((m0 + rl) & 4095);
      float2 cs0 = cstab[pos * 32 + lrow];
      float2 cs1 = cstab[pos * 32 + 16 + lrow];
      float a0 = acc[m][0][r], a2 = acc[m][2][r];
      acc[m][0][r] = a0 * cs0.x - a2 * cs0.y;
      acc[m][2][r] = a2 * cs0.x + a0 * cs0.y;
      float a1 = acc[m][1][r], a3 = acc[m][3][r];
      acc[m][1][r] = a1 * cs1.x - a3 * cs1.y;
      acc[m][3][r] = a3 * cs1.x + a1 * cs1.y;
    }

  const int h = (n0 + wc * 64) >> 6;
  if (!isq) {
    float g4[4], b4[4];
#pragma unroll
    for (int n = 0; n < 4; ++n) { g4[n] = gamma[n * 16 + lrow]; b4[n] = beta[n * 16 + lrow]; }
#pragma unroll
    for (int m = 0; m < 4; ++m)
#pragma unroll
      for (int r = 0; r < 4; ++r) {
        float s1 = acc[m][0][r] + acc[m][1][r] + acc[m][2][r] + acc[m][3][r];
        float s2 = acc[m][0][r] * acc[m][0][r] + acc[m][1][r] * acc[m][1][r] +
                   acc[m][2][r] * acc[m][2][r] + acc[m][3][r] * acc[m][3][r];
#pragma unroll
        for (int mk = 1; mk < 16; mk <<= 1) {
          s1 += __shfl_xor(s1, mk);
          s2 += __shfl_xor(s2, mk);
        }
        float mu = s1 * 0.015625f;
        float var = s2 * 0.015625f - mu * mu;
        float inv = rsqrtf(var + 1e-5f);
#pragma unroll
        for (int n = 0; n < 4; ++n)
          acc[m][n][r] = (acc[m][n][r] - mu) * inv * g4[n] + b4[n];
      }
    const size_t hb = (size_t)((m0 >> 12) * HEADS + h);
#pragma unroll
    for (int m = 0; m < 4; ++m)
#pragma unroll
      for (int r = 0; r < 4; ++r) {
        int pos = (m0 + wr * 64 + m * 16 + lk * 4 + r) & 4095;
#pragma unroll
        for (int n = 0; n < 4; ++n)
          kvn[(hb * SEQ + pos) * DHH + n * 16 + lrow] = (__bf16)acc[m][n][r];
      }
#pragma unroll
    for (int m = 0; m < 4; ++m) {
      int pos0 = (m0 + wr * 64 + m * 16 + lk * 4) & 4095;
      int sp = (pos0 & ~12) | ((pos0 & 4) << 1) | ((pos0 & 8) >> 1);
#pragma unroll
      for (int n = 0; n < 4; ++n) {
        union { __bf16 hh[4]; uint64_t u; } pk;
#pragma unroll
        for (int r = 0; r < 4; ++r) pk.hh[r] = (__bf16)acc[m][n][r];
        *reinterpret_cast<uint64_t*>(kvnT + (hb * DHH + n * 16 + lrow) * SEQ + sp) = pk.u;
      }
    }
  } else {
    const size_t hb = (size_t)((m0 >> 10) * HEADS + h);
#pragma unroll
    for (int m = 0; m < 4; ++m)
#pragma unroll
      for (int r = 0; r < 4; ++r) {
        int qi = (m0 + wr * 64 + m * 16 + lk * 4 + r) & 1023;
#pragma unroll
        for (int n = 0; n < 4; ++n)
          qb[(hb * LATENT + qi) * DHH + n * 16 + lrow] =
              (__bf16)(acc[m][n][r] * 0.18033688011112042f);
      }
  }
}

// ---------------- helpers for flash ----------------
__device__ __forceinline__ float fexp2(float x) {
#if __has_builtin(__builtin_amdgcn_exp2f)
  return __builtin_amdgcn_exp2f(x);
#else
  return exp2f(x);
#endif
}

__device__ __forceinline__ unsigned pk2(float a, float b) {
  union { __bf16 h[2]; unsigned u; } x;
  x.h[0] = (__bf16)a; x.h[1] = (__bf16)b;
  return x.u;
}

// ---------------- flash attention v10: block-shared KV ----------------
// Block = 128 q-rows (4 waves x 32), all waves consume every K/V tile from
// block-shared double-buffered LDS staged ONCE per block via global_load_lds
// (pre-swizzled global source, rule #21). 2-way j-split across blocks keeps
// 2 blocks/CU; itq mirrored so each CU's pair sums to constant work. Wave
// output is final for its rows; j-halves merged by k_fmerge10.
// Schedule per tile: QK(buf) -> issue stage(tt+1,buf^1) -> softmax+PV(buf)
// -> barrier (vmcnt drain lands after ~300cy of compute).
__launch_bounds__(256)
__global__ void k_flash10(const __bf16* __restrict__ qb, const __bf16* __restrict__ kvn,
                          const __bf16* __restrict__ kvnT, float* __restrict__ part) {
  const int bid = blockIdx.x;                  // [0,512)
  const int xcd = bid & 7;
  const int u6 = bid >> 3;                     // [0,64)
  const int jh = u6 & 1;
  int itq = (u6 >> 1) & 7;
  const int grpb = u6 >> 4;                    // [0,4)
  if (grpb >= 2) itq = 7 - itq;                // CU pair balance (bid, bid+256)
  const int bh = xcd + 8 * grpb;               // [0,32)
  const int h = bh & 15, b = bh >> 4;
  const int t = threadIdx.x, l = t & 63, w = t >> 6;
  const int q = l & 31, hi = l >> 5;
  const int iw0 = itq * 128;
  const int iwv = iw0 + w * 32;                // wave's first q-row
  const int i = iwv + q;
  const __bf16* qbase = qb + ((size_t)(b * HEADS + h) * LATENT + iwv) * DHH;
  const __bf16* kbase = kvn + (size_t)(b * HEADS + h) * SEQ * DHH;
  const __bf16* vbase = kvnT + (size_t)(b * HEADS + h) * DHH * SEQ;

  __shared__ __align__(16) __bf16 Kl[2][32][64];   // [buf][key][d], chunk-swizzled
  __shared__ __align__(16) __bf16 Vl[2][64][32];   // [buf][d][key], chunk-swizzled

  // staging map: thread t covers one 16B chunk of each tile
  const int krow = t >> 3, kgc = ((t & 7) ^ (krow & 7)) * 8;   // K: 32 rows x 8 chunks
  const int vrow = t >> 2, vgc = ((t & 3) ^ (vrow & 3)) * 8;   // V: 64 rows x 4 chunks

  bf16x8 qf[4];
#pragma unroll
  for (int c = 0; c < 4; ++c)
    qf[c] = *reinterpret_cast<const bf16x8*>(qbase + (size_t)q * DHH + c * 16 + hi * 8);

  const f32x16 Z = {};
  f32x16 O0 = {}, O1 = {};
  float m_run = -INFINITY, lacc = 0.f;

  const int nt = 4 * itq + 100;                // total 32-key tiles for this block
  const int t0 = (nt * jh) >> 1, t1 = (nt * (jh + 1)) >> 1;
  const int sx = q & 3;

  // prologue stage (tile t0 -> buf 0)
  {
    const int j0 = t0 * 32;
    gload16((char*)&Kl[0][0][0] + t * 16, kbase + (size_t)(j0 + krow) * DHH + kgc);
    gload16((char*)&Vl[0][0][0] + t * 16, vbase + (size_t)vrow * SEQ + j0 + vgc);
  }
  __syncthreads();

  for (int tt = t0; tt < t1; ++tt) {
    const int cur = (tt - t0) & 1;
    const int j0 = tt * 32;
    const char* Kb = (const char*)&Kl[cur][0][0];
    const char* Vb = (const char*)&Vl[cur][0][0];
    // K frags from shared LDS (swizzled chunks)
    bf16x8 kf0 = *reinterpret_cast<const bf16x8*>(Kb + q * 128 + ((0 + hi) ^ (q & 7)) * 16);
    bf16x8 kf1 = *reinterpret_cast<const bf16x8*>(Kb + q * 128 + ((2 + hi) ^ (q & 7)) * 16);
    bf16x8 kf2 = *reinterpret_cast<const bf16x8*>(Kb + q * 128 + ((4 + hi) ^ (q & 7)) * 16);
    bf16x8 kf3 = *reinterpret_cast<const bf16x8*>(Kb + q * 128 + ((6 + hi) ^ (q & 7)) * 16);
    f32x16 S = __builtin_amdgcn_mfma_f32_32x32x16_bf16(kf0, qf[0], Z, 0, 0, 0);
    S = __builtin_amdgcn_mfma_f32_32x32x16_bf16(kf1, qf[1], S, 0, 0, 0);
    S = __builtin_amdgcn_mfma_f32_32x32x16_bf16(kf2, qf[2], S, 0, 0, 0);
    S = __builtin_amdgcn_mfma_f32_32x32x16_bf16(kf3, qf[3], S, 0, 0, 0);
    // issue next tile's stage into the other buffer (drained at loop-end barrier)
    if (tt + 1 < t1) {
      const int j0n = (tt + 1) * 32;
      gload16((char*)&Kl[cur ^ 1][0][0] + t * 16, kbase + (size_t)(j0n + krow) * DHH + kgc);
      gload16((char*)&Vl[cur ^ 1][0][0] + t * 16, vbase + (size_t)vrow * SEQ + j0n + vgc);
    }
    // mask: j - HIST > i
    if (j0 + 31 > iwv + HISTC) {
#pragma unroll
      for (int r = 0; r < 16; ++r) {
        int j = j0 + (r & 3) + 8 * (r >> 2) + 4 * hi;
        if (j > i + HISTC) S[r] = -1e30f;
      }
    }
    // lane-local max
    float u1 = fmaxf(fmaxf(S[0], S[1]), S[2]);
    float u2 = fmaxf(fmaxf(S[3], S[4]), S[5]);
    float u3 = fmaxf(fmaxf(S[6], S[7]), S[8]);
    float u4 = fmaxf(fmaxf(S[9], S[10]), S[11]);
    float u5 = fmaxf(fmaxf(S[12], S[13]), S[14]);
    float pm = fmaxf(fmaxf(fmaxf(u1, u2), u3), fmaxf(fmaxf(u4, u5), S[15]));
    // defer-max
    if (__any(pm > m_run + 8.0f)) {
      pm = fmaxf(pm, __shfl_xor(pm, 32));
      float mn = fmaxf(m_run, pm);
      float sc = fexp2(m_run - mn);
      m_run = mn;
      lacc *= sc;
#pragma unroll
      for (int r = 0; r < 16; ++r) { O0[r] *= sc; O1[r] *= sc; }
    }
    // P = 2^(S-m); lane-local sum
    float p[16];
#pragma unroll
    for (int r = 0; r < 16; ++r) p[r] = fexp2(S[r] - m_run);
    float s8[8];
#pragma unroll
    for (int r = 0; r < 8; ++r) s8[r] = p[r] + p[r + 8];
    lacc += ((s8[0] + s8[4]) + (s8[1] + s8[5])) + ((s8[2] + s8[6]) + (s8[3] + s8[7]));
    // PV B-frags = own p's (sigma-permuted V)
    union { unsigned u[4]; bf16x8 v; } pf0, pf1;
    pf0.u[0] = pk2(p[0], p[1]);   pf0.u[1] = pk2(p[2], p[3]);
    pf0.u[2] = pk2(p[4], p[5]);   pf0.u[3] = pk2(p[6], p[7]);
    pf1.u[0] = pk2(p[8], p[9]);   pf1.u[1] = pk2(p[10], p[11]);
    pf1.u[2] = pk2(p[12], p[13]); pf1.u[3] = pk2(p[14], p[15]);
    {
      bf16x8 va00 = *reinterpret_cast<const bf16x8*>(Vb + q * 64 + (hi ^ sx) * 16);
      bf16x8 va01 = *reinterpret_cast<const bf16x8*>(Vb + q * 64 + ((2 + hi) ^ sx) * 16);
      bf16x8 va10 = *reinterpret_cast<const bf16x8*>(Vb + (32 + q) * 64 + (hi ^ sx) * 16);
      bf16x8 va11 = *reinterpret_cast<const bf16x8*>(Vb + (32 + q) * 64 + ((2 + hi) ^ sx) * 16);
      O0 = __builtin_amdgcn_mfma_f32_32x32x16_bf16(va00, pf0.v, O0, 0, 0, 0);
      O0 = __builtin_amdgcn_mfma_f32_32x32x16_bf16(va01, pf1.v, O0, 0, 0, 0);
      O1 = __builtin_amdgcn_mfma_f32_32x32x16_bf16(va10, pf0.v, O1, 0, 0, 0);
      O1 = __builtin_amdgcn_mfma_f32_32x32x16_bf16(va11, pf1.v, O1, 0, 0, 0);
    }
    __syncthreads();   // drain stage(tt+1), sync readers before buf reuse
  }
  float l_run = lacc + __shfl_xor(lacc, 32);

  // -------- wave-final partial dump (reg-major, coalesced) --------
  const int pidx = (bh * 8 + itq) * 2 + jh;
  float* pw = part + (size_t)(pidx * 4 + w) * 34 * 64;
#pragma unroll
  for (int r = 0; r < 16; ++r) pw[r * 64 + l] = O0[r];
#pragma unroll
  for (int r = 0; r < 16; ++r) pw[(16 + r) * 64 + l] = O1[r];
  pw[32 * 64 + l] = m_run;
  pw[33 * 64 + l] = l_run;
}

// ---------------- merge the 2 j-split partials -> aout (bf16) ----------------
__global__ void k_fmerge10(const float* __restrict__ part, __bf16* __restrict__ aout) {
  const int u = blockIdx.x;                    // [0,256) = bh*8 + itq
  const int bh = u >> 3, itq = u & 7;
  const int b = bh >> 4, h = bh & 15;
  const int t = threadIdx.x;
  const int w = t >> 6, sub = t & 63, q = sub & 31, hi = sub >> 5;
  const float* pa = part + (size_t)((u * 2 + 0) * 4 + w) * 34 * 64;
  const float* pb = part + (size_t)((u * 2 + 1) * 4 + w) * 34 * 64;
  float m0 = pa[32 * 64 + sub], l0 = pa[33 * 64 + sub];
  float m1 = pb[32 * 64 + sub], l1 = pb[33 * 64 + sub];
  float mm = fmaxf(m0, m1);
  float sc0 = fexp2(m0 - mm), sc1 = fexp2(m1 - mm);
  float inv = 1.f / (l0 * sc0 + l1 * sc1);
  const int row = itq * 128 + w * 32 + q;
  __bf16* orow = aout + ((size_t)(b * LATENT) + row) * DIMC + h * DHH;
#pragma unroll
  for (int g = 0; g < 4; ++g) {
    union { __bf16 hh[4]; uint2 u2; } pk;
#pragma unroll
    for (int e = 0; e < 4; ++e)
      pk.hh[e] = (__bf16)((pa[(4 * g + e) * 64 + sub] * sc0 +
                           pb[(4 * g + e) * 64 + sub] * sc1) * inv);
    *reinterpret_cast<uint2*>(orow + 8 * g + 4 * hi) = pk.u2;
#pragma unroll
    for (int e = 0; e < 4; ++e)
      pk.hh[e] = (__bf16)((pa[(16 + 4 * g + e) * 64 + sub] * sc0 +
                           pb[(16 + 4 * g + e) * 64 + sub] * sc1) * inv);
    *reinterpret_cast<uint2*>(orow + 32 + 8 * g + 4 * hi) = pk.u2;
  }
}

// ---------------- host launcher ----------------
extern "C" void kernel_launch(void* const* d_in, const int* in_sizes, int n_in,
                              void* d_out, int out_size, void* d_ws, size_t ws_size,
                              hipStream_t stream) {
  const float* x = (const float*)d_in[0];
  const float* Wq = (const float*)d_in[1];
  const float* Wkv = (const float*)d_in[2];
  const float* Wo = (const float*)d_in[3];
  const float* bo = (const float*)d_in[4];
  const float* gamma = (const float*)d_in[5];
  const float* beta = (const float*)d_in[6];

  char* ws = (char*)d_ws;
  size_t o = 0;
  __bf16* x16 = (__bf16*)(ws + o);  o += (size_t)BATCH * SEQ * DIMC * 2;
  __bf16* wq16 = (__bf16*)(ws + o); o += (size_t)DIMC * DIMC * 2;
  __bf16* wkv16 = (__bf16*)(ws + o); o += (size_t)DIMC * DIMC * 2;
  __bf16* wo16 = (__bf16*)(ws + o); o += (size_t)DIMC * DIMC * 2;
  float2* cstab = (float2*)(ws + o); o += (size_t)SEQ * 32 * 8;
  __bf16* kvn = (__bf16*)(ws + o);  o += (size_t)BATCH * HEADS * SEQ * DHH * 2;
  __bf16* kvnT = (__bf16*)(ws + o); o += (size_t)BATCH * HEADS * SEQ * DHH * 2;
  __bf16* qb = (__bf16*)(ws + o);   o += (size_t)BATCH * HEADS * LATENT * DHH * 2;
  __bf16* aout = (__bf16*)(ws + o); o += (size_t)BATCH * LATENT * DIMC * 2;
  float* part = (float*)(ws + o);   o += (size_t)512 * 4 * 34 * 64 * 4;

  k_prep<<<4096, 256, 0, stream>>>(x, Wq, Wkv, Wo, x16, wq16, wkv16, wo16, cstab);
  k_gemmqkv<<<640, 256, 0, stream>>>(x16, wkv16, wq16, kvn, kvnT, qb, gamma, beta, cstab);
  k_flash10<<<512, 256, 0, stream>>>(qb, kvn, kvnT, part);
  k_fmerge10<<<256, 256, 0, stream>>>(part, aout);
  k_gemm<1><<<128, 256, 0, stream>>>(aout, wo16, (float*)d_out, bo, 2048, 1024, 1024);
}

// Round 14
// 152.795 us; speedup vs baseline: 1.1505x; 1.0294x over previous
//
#include <hip/hip_runtime.h>
#include <hip/hip_bf16.h>
#include <cstdint>

#define DIMC 1024
#define HEADS 16
#define DHH 64
#define SEQ 4096
#define LATENT 1024
#define HISTC 3072
#define BATCH 2

typedef __attribute__((ext_vector_type(8))) __bf16 bf16x8;
typedef __attribute__((ext_vector_type(4))) float f32x4;
typedef __attribute__((ext_vector_type(16))) float f32x16;

// ---------------- fused prep: x->bf16, 3 weights->bf16, RoPE cos/sin table ----
__global__ void k_prep(const float* __restrict__ x, const float* __restrict__ Wq,
                       const float* __restrict__ Wkv, const float* __restrict__ Wo,
                       __bf16* __restrict__ x16, __bf16* __restrict__ wq16,
                       __bf16* __restrict__ wkv16, __bf16* __restrict__ wo16,
                       float2* __restrict__ cs) {
  int bidx = blockIdx.x;
  if (bidx < 2048) {
    int base = bidx * 256 + threadIdx.x;
#pragma unroll
    for (int k = 0; k < 4; ++k) {
      int i = base + k * 524288;
      float4 v = reinterpret_cast<const float4*>(x)[i];
      union { __bf16 h[4]; uint64_t u; } p;
      p.h[0] = (__bf16)v.x; p.h[1] = (__bf16)v.y;
      p.h[2] = (__bf16)v.z; p.h[3] = (__bf16)v.w;
      reinterpret_cast<uint64_t*>(x16)[i] = p.u;
    }
  } else if (bidx < 3584) {
    int id = bidx - 2048;
    const float* src; __bf16* dst;
    if (id < 512) { src = Wq; dst = wq16; }
    else if (id < 1024) { src = Wkv; dst = wkv16; id -= 512; }
    else { src = Wo; dst = wo16; id -= 1024; }
#pragma unroll
    for (int k = 0; k < 2; ++k) {
      int idx = id * 512 + k * 256 + threadIdx.x;
      float4 v = reinterpret_cast<const float4*>(src)[idx];
      union { __bf16 h[4]; uint64_t u; } p;
      p.h[0] = (__bf16)v.x; p.h[1] = (__bf16)v.y;
      p.h[2] = (__bf16)v.z; p.h[3] = (__bf16)v.w;
      reinterpret_cast<uint64_t*>(dst)[idx] = p.u;
    }
  } else {
    int idx = (bidx - 3584) * 256 + threadIdx.x;   // 4096*32 entries
    int pos = idx >> 5, f = idx & 31;
    float invf = exp2f(-(float)f * 0.41524101186f);  // log2(10000)/32
    float s, c;
    sincosf((float)pos * invf, &s, &c);
    cs[idx] = make_float2(c, s);
  }
}

// ---------------- async global->LDS 16B ----------------
__device__ __forceinline__ void gload16(void* lds, const void* g) {
  __builtin_amdgcn_global_load_lds(
      (const __attribute__((address_space(1))) unsigned int*)g,
      (__attribute__((address_space(3))) unsigned int*)lds, 16, 0, 0);
}

// ---------------- plain GEMM (o-proj): C = A @ Bw^T + bias ----
template<int BIAS>
__launch_bounds__(256)
__global__ void k_gemm(const __bf16* __restrict__ A, const __bf16* __restrict__ Bw,
                       float* __restrict__ C, const float* __restrict__ bias,
                       int M, int N, int K) {
  __shared__ __align__(16) char lds[16384];
  const int t = threadIdx.x;
  const int l = t & 63, w = t >> 6;
  const int wr = w >> 1, wc = w & 1;
  const int mblocks = M >> 7;
  const int m0 = (blockIdx.x % mblocks) * 128, n0 = (blockIdx.x / mblocks) * 128;
  const int lrow = l & 15, lk = l >> 4;
  f32x4 acc[4][4] = {};

  for (int k0 = 0; k0 < K; k0 += 32) {
    if (k0) __syncthreads();
#pragma unroll
    for (int i = 0; i < 2; ++i) {
      int c = i * 256 + t;
      int row = c >> 2, kc = c & 3;
      gload16(lds + c * 16, A + (size_t)(m0 + row) * K + k0 + kc * 8);
      gload16(lds + 8192 + c * 16, Bw + (size_t)(n0 + row) * K + k0 + kc * 8);
    }
    __syncthreads();
    bf16x8 af[4], bfr[4];
#pragma unroll
    for (int m = 0; m < 4; ++m)
      af[m] = *reinterpret_cast<const bf16x8*>(lds + (wr * 64 + m * 16 + lrow) * 64 + lk * 16);
#pragma unroll
    for (int n = 0; n < 4; ++n)
      bfr[n] = *reinterpret_cast<const bf16x8*>(lds + 8192 + (wc * 64 + n * 16 + lrow) * 64 + lk * 16);
#pragma unroll
    for (int m = 0; m < 4; ++m)
#pragma unroll
      for (int n = 0; n < 4; ++n)
        acc[m][n] = __builtin_amdgcn_mfma_f32_16x16x32_bf16(af[m], bfr[n], acc[m][n], 0, 0, 0);
  }

#pragma unroll
  for (int m = 0; m < 4; ++m)
#pragma unroll
    for (int n = 0; n < 4; ++n)
#pragma unroll
      for (int r = 0; r < 4; ++r) {
        int row = m0 + wr * 64 + m * 16 + (l >> 4) * 4 + r;
        int col = n0 + wc * 64 + n * 16 + (l & 15);
        float v = acc[m][n][r];
        if (BIAS) v += bias[col];
        C[(size_t)row * N + col] = v;
      }
}

// ---------------- fused QKV GEMM: kv-proj(+RoPE+LN) and q-proj(+RoPE+scale) ----
__launch_bounds__(256)
__global__ void k_gemmqkv(const __bf16* __restrict__ x16,
                          const __bf16* __restrict__ wkv16,
                          const __bf16* __restrict__ wq16,
                          __bf16* __restrict__ kvn, __bf16* __restrict__ kvnT,
                          __bf16* __restrict__ qb,
                          const float* __restrict__ gamma,
                          const float* __restrict__ beta,
                          const float2* __restrict__ cstab) {
  __shared__ __align__(16) char lds[16384];
  const int t = threadIdx.x, l = t & 63, w = t >> 6;
  const int wr = w >> 1, wc = w & 1;
  const int by = blockIdx.x % 80;
  const bool isq = by >= 64;
  const int m0 = (isq ? (by - 64) : by) * 128;
  const int n0 = (blockIdx.x / 80) * 128;
  const __bf16* Bw = isq ? wq16 : wkv16;
  const int lrow = l & 15, lk = l >> 4;
  f32x4 acc[4][4] = {};

  for (int k0 = 0; k0 < 1024; k0 += 32) {
    if (k0) __syncthreads();
#pragma unroll
    for (int i = 0; i < 2; ++i) {
      int c = i * 256 + t;
      int row = c >> 2, kc = c & 3;
      int mi = m0 + row;
      if (isq) mi += HISTC + (mi >> 10) * HISTC;
      gload16(lds + c * 16, x16 + (size_t)mi * 1024 + k0 + kc * 8);
      gload16(lds + 8192 + c * 16, Bw + (size_t)(n0 + row) * 1024 + k0 + kc * 8);
    }
    __syncthreads();
    bf16x8 af[4], bfr[4];
#pragma unroll
    for (int m = 0; m < 4; ++m)
      af[m] = *reinterpret_cast<const bf16x8*>(lds + (wr * 64 + m * 16 + lrow) * 64 + lk * 16);
#pragma unroll
    for (int n = 0; n < 4; ++n)
      bfr[n] = *reinterpret_cast<const bf16x8*>(lds + 8192 + (wc * 64 + n * 16 + lrow) * 64 + lk * 16);
#pragma unroll
    for (int m = 0; m < 4; ++m)
#pragma unroll
      for (int n = 0; n < 4; ++n)
        acc[m][n] = __builtin_amdgcn_mfma_f32_16x16x32_bf16(af[m], bfr[n], acc[m][n], 0, 0, 0);
  }

  // ---- RoPE in place via table ----
#pragma unroll
  for (int m = 0; m < 4; ++m)
#pragma unroll
    for (int r = 0; r < 4; ++r) {
      int rl = wr * 64 + m * 16 + lk * 4 + r;
      int pos = isq ? (HISTC + ((m0 + rl) & 1023)) : ((m0 + rl) & 4095);
      float2 cs0 = cstab[pos * 32 + lrow];
      float2 cs1 = cstab[pos * 32 + 16 + lrow];
      float a0 = acc[m][0][r], a2 = acc[m][2][r];
      acc[m][0][r] = a0 * cs0.x - a2 * cs0.y;
      acc[m][2][r] = a2 * cs0.x + a0 * cs0.y;
      float a1 = acc[m][1][r], a3 = acc[m][3][r];
      acc[m][1][r] = a1 * cs1.x - a3 * cs1.y;
      acc[m][3][r] = a3 * cs1.x + a1 * cs1.y;
    }

  const int h = (n0 + wc * 64) >> 6;
  if (!isq) {
    float g4[4], b4[4];
#pragma unroll
    for (int n = 0; n < 4; ++n) { g4[n] = gamma[n * 16 + lrow]; b4[n] = beta[n * 16 + lrow]; }
#pragma unroll
    for (int m = 0; m < 4; ++m)
#pragma unroll
      for (int r = 0; r < 4; ++r) {
        float s1 = acc[m][0][r] + acc[m][1][r] + acc[m][2][r] + acc[m][3][r];
        float s2 = acc[m][0][r] * acc[m][0][r] + acc[m][1][r] * acc[m][1][r] +
                   acc[m][2][r] * acc[m][2][r] + acc[m][3][r] * acc[m][3][r];
#pragma unroll
        for (int mk = 1; mk < 16; mk <<= 1) {
          s1 += __shfl_xor(s1, mk);
          s2 += __shfl_xor(s2, mk);
        }
        float mu = s1 * 0.015625f;
        float var = s2 * 0.015625f - mu * mu;
        float inv = rsqrtf(var + 1e-5f);
#pragma unroll
        for (int n = 0; n < 4; ++n)
          acc[m][n][r] = (acc[m][n][r] - mu) * inv * g4[n] + b4[n];
      }
    const size_t hb = (size_t)((m0 >> 12) * HEADS + h);
#pragma unroll
    for (int m = 0; m < 4; ++m)
#pragma unroll
      for (int r = 0; r < 4; ++r) {
        int pos = (m0 + wr * 64 + m * 16 + lk * 4 + r) & 4095;
#pragma unroll
        for (int n = 0; n < 4; ++n)
          kvn[(hb * SEQ + pos) * DHH + n * 16 + lrow] = (__bf16)acc[m][n][r];
      }
#pragma unroll
    for (int m = 0; m < 4; ++m) {
      int pos0 = (m0 + wr * 64 + m * 16 + lk * 4) & 4095;
      int sp = (pos0 & ~12) | ((pos0 & 4) << 1) | ((pos0 & 8) >> 1);
#pragma unroll
      for (int n = 0; n < 4; ++n) {
        union { __bf16 hh[4]; uint64_t u; } pk;
#pragma unroll
        for (int r = 0; r < 4; ++r) pk.hh[r] = (__bf16)acc[m][n][r];
        *reinterpret_cast<uint64_t*>(kvnT + (hb * DHH + n * 16 + lrow) * SEQ + sp) = pk.u;
      }
    }
  } else {
    const size_t hb = (size_t)((m0 >> 10) * HEADS + h);
#pragma unroll
    for (int m = 0; m < 4; ++m)
#pragma unroll
      for (int r = 0; r < 4; ++r) {
        int qi = (m0 + wr * 64 + m * 16 + lk * 4 + r) & 1023;
#pragma unroll
        for (int n = 0; n < 4; ++n)
          qb[(hb * LATENT + qi) * DHH + n * 16 + lrow] =
              (__bf16)(acc[m][n][r] * 0.18033688011112042f);
      }
  }
}

// ---------------- helpers for flash ----------------
__device__ __forceinline__ float fexp2(float x) {
#if __has_builtin(__builtin_amdgcn_exp2f)
  return __builtin_amdgcn_exp2f(x);
#else
  return exp2f(x);
#endif
}

__device__ __forceinline__ unsigned pk2(float a, float b) {
  union { __bf16 h[2]; unsigned u; } x;
  x.h[0] = (__bf16)a; x.h[1] = (__bf16)b;
  return x.u;
}

// ---------------- flash attention v11: block-shared KV, 64-key iterations ----
// As flash10 (block = 128 q-rows, KV staged once/block via global_load_lds,
// 2-way j-split across blocks, fmerge) but each barrier-delimited iteration
// stages and consumes TWO 32-key subtiles (a/b): barrier count halves, the
// pre-barrier vmcnt(0) drain amortizes over ~2x compute.
__launch_bounds__(256)
__global__ void k_flash11(const __bf16* __restrict__ qb, const __bf16* __restrict__ kvn,
                          const __bf16* __restrict__ kvnT, float* __restrict__ part) {
  const int bid = blockIdx.x;                  // [0,512)
  const int xcd = bid & 7;
  const int u6 = bid >> 3;                     // [0,64)
  const int jh = u6 & 1;
  int itq = (u6 >> 1) & 7;
  const int grpb = u6 >> 4;                    // [0,4)
  if (grpb >= 2) itq = 7 - itq;                // CU pair balance
  const int bh = xcd + 8 * grpb;               // [0,32)
  const int h = bh & 15, b = bh >> 4;
  const int t = threadIdx.x, l = t & 63, w = t >> 6;
  const int q = l & 31, hi = l >> 5;
  const int iw0 = itq * 128;
  const int iwv = iw0 + w * 32;                // wave's first q-row
  const int i = iwv + q;
  const __bf16* qbase = qb + ((size_t)(b * HEADS + h) * LATENT + iwv) * DHH;
  const __bf16* kbase = kvn + (size_t)(b * HEADS + h) * SEQ * DHH;
  const __bf16* vbase = kvnT + (size_t)(b * HEADS + h) * DHH * SEQ;

  __shared__ __align__(16) __bf16 Kl[2][2][32][64];   // [buf][sub][key][d]
  __shared__ __align__(16) __bf16 Vl[2][2][64][32];   // [buf][sub][d][key]

  // staging maps (identical to flash10, per 32-key subtile)
  const int krow = t >> 3, kgc = ((t & 7) ^ (krow & 7)) * 8;   // K: 32 rows x 8 chunks
  const int vrow = t >> 2, vgc = ((t & 3) ^ (vrow & 3)) * 8;   // V: 64 rows x 4 chunks

  bf16x8 qf[4];
#pragma unroll
  for (int c = 0; c < 4; ++c)
    qf[c] = *reinterpret_cast<const bf16x8*>(qbase + (size_t)q * DHH + c * 16 + hi * 8);

  const f32x16 Z = {};
  f32x16 O0 = {}, O1 = {};
  float m_run = -INFINITY, lacc = 0.f;

  const int nt = 4 * itq + 100;                // 32-key tiles (even)
  const int t0 = (nt * jh) >> 1, t1 = (nt * (jh + 1)) >> 1;  // both even
  const int g0 = t0 >> 1, g1 = t1 >> 1;        // 64-key groups
  const int sx = q & 3;

  // prologue: stage group g0 -> buf 0 (both subtiles)
  {
    const int ja = g0 * 64;
    gload16((char*)&Kl[0][0][0][0] + t * 16, kbase + (size_t)(ja + krow) * DHH + kgc);
    gload16((char*)&Kl[0][1][0][0] + t * 16, kbase + (size_t)(ja + 32 + krow) * DHH + kgc);
    gload16((char*)&Vl[0][0][0][0] + t * 16, vbase + (size_t)vrow * SEQ + ja + vgc);
    gload16((char*)&Vl[0][1][0][0] + t * 16, vbase + (size_t)vrow * SEQ + ja + 32 + vgc);
  }
  __syncthreads();

  for (int g = g0; g < g1; ++g) {
    const int cur = (g - g0) & 1;
    const int ja = g * 64, jb = ja + 32;
    // ---------------- subtile a: QK ----------------
    const char* Ka = (const char*)&Kl[cur][0][0][0];
    const char* Va = (const char*)&Vl[cur][0][0][0];
    bf16x8 kf0 = *reinterpret_cast<const bf16x8*>(Ka + q * 128 + ((0 + hi) ^ (q & 7)) * 16);
    bf16x8 kf1 = *reinterpret_cast<const bf16x8*>(Ka + q * 128 + ((2 + hi) ^ (q & 7)) * 16);
    bf16x8 kf2 = *reinterpret_cast<const bf16x8*>(Ka + q * 128 + ((4 + hi) ^ (q & 7)) * 16);
    bf16x8 kf3 = *reinterpret_cast<const bf16x8*>(Ka + q * 128 + ((6 + hi) ^ (q & 7)) * 16);
    f32x16 S = __builtin_amdgcn_mfma_f32_32x32x16_bf16(kf0, qf[0], Z, 0, 0, 0);
    S = __builtin_amdgcn_mfma_f32_32x32x16_bf16(kf1, qf[1], S, 0, 0, 0);
    S = __builtin_amdgcn_mfma_f32_32x32x16_bf16(kf2, qf[2], S, 0, 0, 0);
    S = __builtin_amdgcn_mfma_f32_32x32x16_bf16(kf3, qf[3], S, 0, 0, 0);
    // issue next group's stage into the other buffer
    if (g + 1 < g1) {
      const int jn = (g + 1) * 64;
      gload16((char*)&Kl[cur ^ 1][0][0][0] + t * 16, kbase + (size_t)(jn + krow) * DHH + kgc);
      gload16((char*)&Kl[cur ^ 1][1][0][0] + t * 16, kbase + (size_t)(jn + 32 + krow) * DHH + kgc);
      gload16((char*)&Vl[cur ^ 1][0][0][0] + t * 16, vbase + (size_t)vrow * SEQ + jn + vgc);
      gload16((char*)&Vl[cur ^ 1][1][0][0] + t * 16, vbase + (size_t)vrow * SEQ + jn + 32 + vgc);
    }
    // ---------------- subtile a: softmax + PV ----------------
    if (ja + 31 > iwv + HISTC) {
#pragma unroll
      for (int r = 0; r < 16; ++r) {
        int j = ja + (r & 3) + 8 * (r >> 2) + 4 * hi;
        if (j > i + HISTC) S[r] = -1e30f;
      }
    }
    {
      float u1 = fmaxf(fmaxf(S[0], S[1]), S[2]);
      float u2 = fmaxf(fmaxf(S[3], S[4]), S[5]);
      float u3 = fmaxf(fmaxf(S[6], S[7]), S[8]);
      float u4 = fmaxf(fmaxf(S[9], S[10]), S[11]);
      float u5 = fmaxf(fmaxf(S[12], S[13]), S[14]);
      float pm = fmaxf(fmaxf(fmaxf(u1, u2), u3), fmaxf(fmaxf(u4, u5), S[15]));
      if (__any(pm > m_run + 8.0f)) {
        pm = fmaxf(pm, __shfl_xor(pm, 32));
        float mn = fmaxf(m_run, pm);
        float sc = fexp2(m_run - mn);
        m_run = mn;
        lacc *= sc;
#pragma unroll
        for (int r = 0; r < 16; ++r) { O0[r] *= sc; O1[r] *= sc; }
      }
      float p[16];
#pragma unroll
      for (int r = 0; r < 16; ++r) p[r] = fexp2(S[r] - m_run);
      float s8[8];
#pragma unroll
      for (int r = 0; r < 8; ++r) s8[r] = p[r] + p[r + 8];
      lacc += ((s8[0] + s8[4]) + (s8[1] + s8[5])) + ((s8[2] + s8[6]) + (s8[3] + s8[7]));
      union { unsigned u[4]; bf16x8 v; } pf0, pf1;
      pf0.u[0] = pk2(p[0], p[1]);   pf0.u[1] = pk2(p[2], p[3]);
      pf0.u[2] = pk2(p[4], p[5]);   pf0.u[3] = pk2(p[6], p[7]);
      pf1.u[0] = pk2(p[8], p[9]);   pf1.u[1] = pk2(p[10], p[11]);
      pf1.u[2] = pk2(p[12], p[13]); pf1.u[3] = pk2(p[14], p[15]);
      bf16x8 va00 = *reinterpret_cast<const bf16x8*>(Va + q * 64 + (hi ^ sx) * 16);
      bf16x8 va01 = *reinterpret_cast<const bf16x8*>(Va + q * 64 + ((2 + hi) ^ sx) * 16);
      bf16x8 va10 = *reinterpret_cast<const bf16x8*>(Va + (32 + q) * 64 + (hi ^ sx) * 16);
      bf16x8 va11 = *reinterpret_cast<const bf16x8*>(Va + (32 + q) * 64 + ((2 + hi) ^ sx) * 16);
      O0 = __builtin_amdgcn_mfma_f32_32x32x16_bf16(va00, pf0.v, O0, 0, 0, 0);
      O0 = __builtin_amdgcn_mfma_f32_32x32x16_bf16(va01, pf1.v, O0, 0, 0, 0);
      O1 = __builtin_amdgcn_mfma_f32_32x32x16_bf16(va10, pf0.v, O1, 0, 0, 0);
      O1 = __builtin_amdgcn_mfma_f32_32x32x16_bf16(va11, pf1.v, O1, 0, 0, 0);
    }
    // ---------------- subtile b ----------------
    const char* Kb = (const char*)&Kl[cur][1][0][0];
    const char* Vb = (const char*)&Vl[cur][1][0][0];
    bf16x8 kg0 = *reinterpret_cast<const bf16x8*>(Kb + q * 128 + ((0 + hi) ^ (q & 7)) * 16);
    bf16x8 kg1 = *reinterpret_cast<const bf16x8*>(Kb + q * 128 + ((2 + hi) ^ (q & 7)) * 16);
    bf16x8 kg2 = *reinterpret_cast<const bf16x8*>(Kb + q * 128 + ((4 + hi) ^ (q & 7)) * 16);
    bf16x8 kg3 = *reinterpret_cast<const bf16x8*>(Kb + q * 128 + ((6 + hi) ^ (q & 7)) * 16);
    f32x16 T = __builtin_amdgcn_mfma_f32_32x32x16_bf16(kg0, qf[0], Z, 0, 0, 0);
    T = __builtin_amdgcn_mfma_f32_32x32x16_bf16(kg1, qf[1], T, 0, 0, 0);
    T = __builtin_amdgcn_mfma_f32_32x32x16_bf16(kg2, qf[2], T, 0, 0, 0);
    T = __builtin_amdgcn_mfma_f32_32x32x16_bf16(kg3, qf[3], T, 0, 0, 0);
    if (jb + 31 > iwv + HISTC) {
#pragma unroll
      for (int r = 0; r < 16; ++r) {
        int j = jb + (r & 3) + 8 * (r >> 2) + 4 * hi;
        if (j > i + HISTC) T[r] = -1e30f;
      }
    }
    {
      float u1 = fmaxf(fmaxf(T[0], T[1]), T[2]);
      float u2 = fmaxf(fmaxf(T[3], T[4]), T[5]);
      float u3 = fmaxf(fmaxf(T[6], T[7]), T[8]);
      float u4 = fmaxf(fmaxf(T[9], T[10]), T[11]);
      float u5 = fmaxf(fmaxf(T[12], T[13]), T[14]);
      float pm = fmaxf(fmaxf(fmaxf(u1, u2), u3), fmaxf(fmaxf(u4, u5), T[15]));
      if (__any(pm > m_run + 8.0f)) {
        pm = fmaxf(pm, __shfl_xor(pm, 32));
        float mn = fmaxf(m_run, pm);
        float sc = fexp2(m_run - mn);
        m_run = mn;
        lacc *= sc;
#pragma unroll
        for (int r = 0; r < 16; ++r) { O0[r] *= sc; O1[r] *= sc; }
      }
      float p[16];
#pragma unroll
      for (int r = 0; r < 16; ++r) p[r] = fexp2(T[r] - m_run);
      float s8[8];
#pragma unroll
      for (int r = 0; r < 8; ++r) s8[r] = p[r] + p[r + 8];
      lacc += ((s8[0] + s8[4]) + (s8[1] + s8[5])) + ((s8[2] + s8[6]) + (s8[3] + s8[7]));
      union { unsigned u[4]; bf16x8 v; } pf0, pf1;
      pf0.u[0] = pk2(p[0], p[1]);   pf0.u[1] = pk2(p[2], p[3]);
      pf0.u[2] = pk2(p[4], p[5]);   pf0.u[3] = pk2(p[6], p[7]);
      pf1.u[0] = pk2(p[8], p[9]);   pf1.u[1] = pk2(p[10], p[11]);
      pf1.u[2] = pk2(p[12], p[13]); pf1.u[3] = pk2(p[14], p[15]);
      bf16x8 vb00 = *reinterpret_cast<const bf16x8*>(Vb + q * 64 + (hi ^ sx) * 16);
      bf16x8 vb01 = *reinterpret_cast<const bf16x8*>(Vb + q * 64 + ((2 + hi) ^ sx) * 16);
      bf16x8 vb10 = *reinterpret_cast<const bf16x8*>(Vb + (32 + q) * 64 + (hi ^ sx) * 16);
      bf16x8 vb11 = *reinterpret_cast<const bf16x8*>(Vb + (32 + q) * 64 + ((2 + hi) ^ sx) * 16);
      O0 = __builtin_amdgcn_mfma_f32_32x32x16_bf16(vb00, pf0.v, O0, 0, 0, 0);
      O0 = __builtin_amdgcn_mfma_f32_32x32x16_bf16(vb01, pf1.v, O0, 0, 0, 0);
      O1 = __builtin_amdgcn_mfma_f32_32x32x16_bf16(vb10, pf0.v, O1, 0, 0, 0);
      O1 = __builtin_amdgcn_mfma_f32_32x32x16_bf16(vb11, pf1.v, O1, 0, 0, 0);
    }
    __syncthreads();   // drain stage(g+1), sync readers before buf reuse
  }
  float l_run = lacc + __shfl_xor(lacc, 32);

  // -------- wave-final partial dump (reg-major, coalesced) --------
  const int pidx = (bh * 8 + itq) * 2 + jh;
  float* pw = part + (size_t)(pidx * 4 + w) * 34 * 64;
#pragma unroll
  for (int r = 0; r < 16; ++r) pw[r * 64 + l] = O0[r];
#pragma unroll
  for (int r = 0; r < 16; ++r) pw[(16 + r) * 64 + l] = O1[r];
  pw[32 * 64 + l] = m_run;
  pw[33 * 64 + l] = l_run;
}

// ---------------- merge the 2 j-split partials -> aout (bf16) ----------------
__global__ void k_fmerge10(const float* __restrict__ part, __bf16* __restrict__ aout) {
  const int u = blockIdx.x;                    // [0,256) = bh*8 + itq
  const int bh = u >> 3, itq = u & 7;
  const int b = bh >> 4, h = bh & 15;
  const int t = threadIdx.x;
  const int w = t >> 6, sub = t & 63, q = sub & 31, hi = sub >> 5;
  const float* pa = part + (size_t)((u * 2 + 0) * 4 + w) * 34 * 64;
  const float* pb = part + (size_t)((u * 2 + 1) * 4 + w) * 34 * 64;
  float m0 = pa[32 * 64 + sub], l0 = pa[33 * 64 + sub];
  float m1 = pb[32 * 64 + sub], l1 = pb[33 * 64 + sub];
  float mm = fmaxf(m0, m1);
  float sc0 = fexp2(m0 - mm), sc1 = fexp2(m1 - mm);
  float inv = 1.f / (l0 * sc0 + l1 * sc1);
  const int row = itq * 128 + w * 32 + q;
  __bf16* orow = aout + ((size_t)(b * LATENT) + row) * DIMC + h * DHH;
#pragma unroll
  for (int g = 0; g < 4; ++g) {
    union { __bf16 hh[4]; uint2 u2; } pk;
#pragma unroll
    for (int e = 0; e < 4; ++e)
      pk.hh[e] = (__bf16)((pa[(4 * g + e) * 64 + sub] * sc0 +
                           pb[(4 * g + e) * 64 + sub] * sc1) * inv);
    *reinterpret_cast<uint2*>(orow + 8 * g + 4 * hi) = pk.u2;
#pragma unroll
    for (int e = 0; e < 4; ++e)
      pk.hh[e] = (__bf16)((pa[(16 + 4 * g + e) * 64 + sub] * sc0 +
                           pb[(16 + 4 * g + e) * 64 + sub] * sc1) * inv);
    *reinterpret_cast<uint2*>(orow + 32 + 8 * g + 4 * hi) = pk.u2;
  }
}

// ---------------- host launcher ----------------
extern "C" void kernel_launch(void* const* d_in, const int* in_sizes, int n_in,
                              void* d_out, int out_size, void* d_ws, size_t ws_size,
                              hipStream_t stream) {
  const float* x = (const float*)d_in[0];
  const float* Wq = (const float*)d_in[1];
  const float* Wkv = (const float*)d_in[2];
  const float* Wo = (const float*)d_in[3];
  const float* bo = (const float*)d_in[4];
  const float* gamma = (const float*)d_in[5];
  const float* beta = (const float*)d_in[6];

  char* ws = (char*)d_ws;
  size_t o = 0;
  __bf16* x16 = (__bf16*)(ws + o);  o += (size_t)BATCH * SEQ * DIMC * 2;
  __bf16* wq16 = (__bf16*)(ws + o); o += (size_t)DIMC * DIMC * 2;
  __bf16* wkv16 = (__bf16*)(ws + o); o += (size_t)DIMC * DIMC * 2;
  __bf16* wo16 = (__bf16*)(ws + o); o += (size_t)DIMC * DIMC * 2;
  float2* cstab = (float2*)(ws + o); o += (size_t)SEQ * 32 * 8;
  __bf16* kvn = (__bf16*)(ws + o);  o += (size_t)BATCH * HEADS * SEQ * DHH * 2;
  __bf16* kvnT = (__bf16*)(ws + o); o += (size_t)BATCH * HEADS * SEQ * DHH * 2;
  __bf16* qb = (__bf16*)(ws + o);   o += (size_t)BATCH * HEADS * LATENT * DHH * 2;
  __bf16* aout = (__bf16*)(ws + o); o += (size_t)BATCH * LATENT * DIMC * 2;
  float* part = (float*)(ws + o);   o += (size_t)512 * 4 * 34 * 64 * 4;

  k_prep<<<4096, 256, 0, stream>>>(x, Wq, Wkv, Wo, x16, wq16, wkv16, wo16, cstab);
  k_gemmqkv<<<640, 256, 0, stream>>>(x16, wkv16, wq16, kvn, kvnT, qb, gamma, beta, cstab);
  k_flash11<<<512, 256, 0, stream>>>(qb, kvn, kvnT, part);
  k_fmerge10<<<256, 256, 0, stream>>>(part, aout);
  k_gemm<1><<<128, 256, 0, stream>>>(aout, wo16, (float*)d_out, bo, 2048, 1024, 1024);
}